// Round 13
// baseline (245.434 us; speedup 1.0000x reference)
//
#include <hip/hip_runtime.h>
#include <stdint.h>

#define GAS __attribute__((address_space(1)))
#define LAS __attribute__((address_space(3)))

typedef __attribute__((ext_vector_type(8))) __bf16 bf16x8;
typedef __attribute__((ext_vector_type(4))) float f32x4;

static constexpr int Bb = 4, Ll = 2048, Dd = 512, Hh = 8, DHd = 64;
static constexpr float LOG2E = 1.4426950408889634f;

__device__ __forceinline__ unsigned short f2bf(float f){
  unsigned u = __float_as_uint(f);
  u += 0x7fffu + ((u >> 16) & 1u);           // round-to-nearest-even
  return (unsigned short)(u >> 16);
}
__device__ __forceinline__ void gload16(const void* g, void* l){
  __builtin_amdgcn_global_load_lds((const GAS void*)g, (LAS void*)l, 16, 0, 0);
}
__device__ __forceinline__ f32x4 mfma16(bf16x8 a, bf16x8 b, f32x4 c){
  return __builtin_amdgcn_mfma_f32_16x16x32_bf16(a, b, c, 0, 0, 0);
}
__device__ __forceinline__ float exp2_hw(float x){   // v_exp_f32 = 2^x
  float r; asm("v_exp_f32 %0, %1" : "=v"(r) : "v"(x)); return r;
}

// BK=32 LDS swizzle: row stride 64B (4 granules of 16B); granule perm by
// (row>>1)&3 gives 2-way bank aliasing on b128 reads (free, m136).
#define SWZ32(r) (((r) >> 1) & 3)

// ---------------------------------------------------------------------------
// fused prep: blocks [0,3072) = weight transposes (f32 (R,C) -> bf16 (C,R));
// blocks [3072, 3072+8192) = per-row sum-of-squares + x f32->bf16 cast + rmax=0.
__global__ __launch_bounds__(256) void prep_all(
    const float* __restrict__ x,
    const float* __restrict__ wq, const float* __restrict__ wk,
    const float* __restrict__ wv, const float* __restrict__ wo,
    const float* __restrict__ w1, const float* __restrict__ w2,
    unsigned short* __restrict__ xbf, float* __restrict__ sq,
    float* __restrict__ rmax,
    unsigned short* __restrict__ wqkvT, unsigned short* __restrict__ woT,
    unsigned short* __restrict__ w1T, unsigned short* __restrict__ w2T)
{
  __shared__ float t[32][33];
  __shared__ float red[4];
  int bid = blockIdx.x;
  if (bid >= 3072){
    // ---- sumsq + cast + rmax zero ----
    int row = bid - 3072, tid = threadIdx.x;
    float2 v = ((const float2*)(x + (size_t)row * Dd))[tid];
    ((unsigned*)(xbf + (size_t)row * Dd))[tid] =
        (unsigned)f2bf(v.x) | ((unsigned)f2bf(v.y) << 16);
    float s2 = v.x * v.x + v.y * v.y;
    #pragma unroll
    for (int s = 1; s < 64; s <<= 1) s2 += __shfl_xor(s2, s, 64);
    if ((tid & 63) == 0) red[tid >> 6] = s2;
    __syncthreads();
    if (tid == 0){
      sq[row] = red[0] + red[1] + red[2] + red[3];
      rmax[row] = 0.f;
    }
    return;
  }
  // ---- weight transpose ----
  const float* in; unsigned short* out; int R, C, bx, by;
  if (bid < 1024){
    int s = bid >> 8, tt = bid & 255;
    in  = s == 0 ? wq : s == 1 ? wk : s == 2 ? wv : wo;
    out = s == 3 ? woT : wqkvT + s * 512 * 512;
    R = 512; C = 512; bx = tt & 15; by = tt >> 4;
  } else if (bid < 2048){
    int tt = bid - 1024; in = w1; out = w1T; R = 512; C = 2048; bx = tt & 63; by = tt >> 6;
  } else {
    int tt = bid - 2048; in = w2; out = w2T; R = 2048; C = 512; bx = tt & 15; by = tt >> 4;
  }
  int tx = threadIdx.x & 31, ty = threadIdx.x >> 5;
  int c0 = bx * 32, r0 = by * 32;
  #pragma unroll
  for (int j = 0; j < 32; j += 8) t[ty + j][tx] = in[(size_t)(r0 + ty + j) * C + c0 + tx];
  __syncthreads();
  #pragma unroll
  for (int j = 0; j < 32; j += 8) out[(size_t)(c0 + ty + j) * R + r0 + tx] = f2bf(t[tx][ty + j]);
}

// ---------------------------------------------------------------------------
// v slice of fused qkv (b,l,1536) -> vT (b,h,dh,l) bf16. grid (L/64,H,B), blk 256
__global__ __launch_bounds__(256) void v_transpose(const unsigned short* __restrict__ qkv,
                                                   unsigned short* __restrict__ vT){
  int b = blockIdx.z, h = blockIdx.y, l0 = blockIdx.x * 64;
  int tid = threadIdx.x;
  __shared__ unsigned short t[64 * 64];
  #pragma unroll
  for (int it = 0; it < 2; ++it){
    int row = tid >> 2;                 // local l
    int c = (tid & 3) + it * 4;         // 16B granule (8 dh)
    uint4 d = *(const uint4*)(qkv + (size_t)(b * Ll + l0 + row) * 1536 + 1024 + h * DHd + c * 8);
    *(uint4*)((char*)t + row * 128 + ((c ^ (row & 7)) << 4)) = d;
  }
  __syncthreads();
  #pragma unroll
  for (int it = 0; it < 2; ++it){
    int dh = tid >> 2;
    int c2 = (tid & 3) + it * 4;        // granule along l (8 l-values)
    unsigned pk[4];
    #pragma unroll
    for (int p = 0; p < 4; ++p){
      unsigned short e0, e1;
      {
        int ll = c2 * 8 + p * 2;
        e0 = *(const unsigned short*)((const char*)t + ll * 128 +
              ((((dh >> 3) ^ (ll & 7))) << 4) + ((dh & 7) << 1));
        ll = c2 * 8 + p * 2 + 1;
        e1 = *(const unsigned short*)((const char*)t + ll * 128 +
              ((((dh >> 3) ^ (ll & 7))) << 4) + ((dh & 7) << 1));
      }
      pk[p] = (unsigned)e0 | ((unsigned)e1 << 16);
    }
    uint4 o; o.x = pk[0]; o.y = pk[1]; o.z = pk[2]; o.w = pk[3];
    *(uint4*)(vT + ((size_t)(b * Hh + h) * DHd + dh) * Ll + l0 + c2 * 8) = o;
  }
}

// ---------------------------------------------------------------------------
// FUSED cdist + QKV GEMM, 128x128 tile, BK=32 2-phase dbuf (32KB LDS ->
// 4 blocks/CU vs 2 at BK=64: doubled co-residency hides the barrier drain).
// blocks [0,544): triangular cdist (136 upper-tri tiles x 4 batches);
// blocks [544,1312): fused QKV projection (12 x 64 tiles), 3-way bias.
__global__ __launch_bounds__(256) void gemm_cq(
    const unsigned short* __restrict__ xbf,
    const unsigned short* __restrict__ wqkvT,
    const float* __restrict__ bq, const float* __restrict__ bk,
    const float* __restrict__ bv,
    unsigned short* __restrict__ cdm, unsigned short* __restrict__ qkv,
    const float* __restrict__ sq, float* __restrict__ rmax,
    const float* __restrict__ mask)
{
  const int bid = blockIdx.x;
  const bool isc = bid < 544;
  const unsigned short *Ap, *Bp;
  int m0, n0, bxx = 0, byy = 0, zb = 0;
  if (isc){
    zb = bid / 136;
    int tt = bid - zb * 136, byv = 0;
    while (tt >= 16 - byv){ tt -= 16 - byv; byv++; }
    byy = byv; bxx = byv + tt;
    m0 = byy * 128; n0 = bxx * 128;
    Ap = xbf + (size_t)zb * Ll * Dd; Bp = Ap;
  } else {
    int t = bid - 544;
    int bx = t % 12, by = t / 12;
    m0 = by * 128; n0 = bx * 128;
    Ap = xbf; Bp = wqkvT;
  }
  const int tid = threadIdx.x, w = tid >> 6, l = tid & 63;
  const int wm = w >> 1, wn = w & 1;
  __shared__ unsigned short lA[2][128 * 32];   // 8KB each buf
  __shared__ unsigned short lB[2][128 * 32];
  f32x4 acc[4][4];
  const f32x4 z4 = {0.f, 0.f, 0.f, 0.f};
  #pragma unroll
  for (int i = 0; i < 4; i++){
    #pragma unroll
    for (int j = 0; j < 4; j++) acc[i][j] = z4;
  }
  const int sc = l & 3;                 // granule within row
  const int lg = l >> 4;

  // prologue: stage k-tile 0
  #pragma unroll
  for (int j = 0; j < 2; j++){
    int row = j * 64 + w * 16 + (l >> 2);
    gload16(Ap + (size_t)(m0 + row) * Dd + ((sc ^ SWZ32(row)) << 3),
            &lA[0][0] + j * 2048 + w * 512);
    gload16(Bp + (size_t)(n0 + row) * Dd + ((sc ^ SWZ32(row)) << 3),
            &lB[0][0] + j * 2048 + w * 512);
  }
  __syncthreads();

  int cur = 0;
  for (int k0 = 0; k0 < Dd; k0 += 32, cur ^= 1){
    if (k0 + 32 < Dd){
      #pragma unroll
      for (int j = 0; j < 2; j++){
        int row = j * 64 + w * 16 + (l >> 2);
        gload16(Ap + (size_t)(m0 + row) * Dd + k0 + 32 + ((sc ^ SWZ32(row)) << 3),
                &lA[cur ^ 1][0] + j * 2048 + w * 512);
        gload16(Bp + (size_t)(n0 + row) * Dd + k0 + 32 + ((sc ^ SWZ32(row)) << 3),
                &lB[cur ^ 1][0] + j * 2048 + w * 512);
      }
    }
    bf16x8 af[4], bvv[4];
    #pragma unroll
    for (int f = 0; f < 4; f++){
      int ra = wm * 64 + f * 16 + (l & 15);
      af[f] = *(const bf16x8*)((const char*)&lA[cur][0] + ra * 64 +
                ((lg ^ SWZ32(ra)) << 4));
      int rb = wn * 64 + f * 16 + (l & 15);
      bvv[f] = *(const bf16x8*)((const char*)&lB[cur][0] + rb * 64 +
                ((lg ^ SWZ32(rb)) << 4));
    }
    #pragma unroll
    for (int mf = 0; mf < 4; mf++){
      #pragma unroll
      for (int nf = 0; nf < 4; nf++)
        acc[mf][nf] = mfma16(af[mf], bvv[nf], acc[mf][nf]);
    }
    __syncthreads();
  }

  if (isc){
    unsigned short* outb = cdm + (size_t)zb * Ll * Ll;
    const float* sqz = sq + zb * Ll;
    const float* mkz = mask + zb * Ll;
    float* rmz = rmax + zb * Ll;
    float sqc[4], mkc[4];
    #pragma unroll
    for (int nf = 0; nf < 4; nf++){
      int col = n0 + wn * 64 + nf * 16 + (l & 15);
      sqc[nf] = sqz[col]; mkc[nf] = mkz[col];
    }
    #pragma unroll
    for (int mf = 0; mf < 4; mf++){
      #pragma unroll
      for (int r = 0; r < 4; r++){
        int row = m0 + wm * 64 + mf * 16 + (l >> 4) * 4 + r;
        float sqi = sqz[row], mi = mkz[row];
        #pragma unroll
        for (int nf = 0; nf < 4; nf++){
          float d2 = sqi + sqc[nf] - 2.f * acc[mf][nf][r];
          acc[mf][nf][r] = sqrtf(fmaxf(d2, 0.f)) * (mi * mkc[nf]) * LOG2E + 8.f;
        }
      }
    }
    #pragma unroll
    for (int mf = 0; mf < 4; mf++){
      #pragma unroll
      for (int r = 0; r < 4; r++){
        int row = m0 + wm * 64 + mf * 16 + (l >> 4) * 4 + r;
        float rm = 0.f;
        #pragma unroll
        for (int nf = 0; nf < 4; nf++){
          int col = n0 + wn * 64 + nf * 16 + (l & 15);
          outb[(size_t)row * Ll + col] = f2bf(acc[mf][nf][r]);
          rm = fmaxf(rm, acc[mf][nf][r]);
        }
        #pragma unroll
        for (int t = 1; t < 16; t <<= 1) rm = fmaxf(rm, __shfl_xor(rm, t, 64));
        if ((l & 15) == 0) atomicMax((int*)(rmz + row), __float_as_int(rm));
      }
    }
    if (bxx != byy){
      #pragma unroll
      for (int nf = 0; nf < 4; nf++){
        int col = n0 + wn * 64 + nf * 16 + (l & 15);
        float cm = 0.f;
        #pragma unroll
        for (int mf = 0; mf < 4; mf++){
          uint2 pk2;
          pk2.x = (unsigned)f2bf(acc[mf][nf][0]) | ((unsigned)f2bf(acc[mf][nf][1]) << 16);
          pk2.y = (unsigned)f2bf(acc[mf][nf][2]) | ((unsigned)f2bf(acc[mf][nf][3]) << 16);
          int rowb = m0 + wm * 64 + mf * 16 + (l >> 4) * 4;
          *(uint2*)(outb + (size_t)col * Ll + rowb) = pk2;
          cm = fmaxf(cm, fmaxf(fmaxf(acc[mf][nf][0], acc[mf][nf][1]),
                               fmaxf(acc[mf][nf][2], acc[mf][nf][3])));
        }
        cm = fmaxf(cm, __shfl_xor(cm, 16, 64));
        cm = fmaxf(cm, __shfl_xor(cm, 32, 64));
        if ((l >> 4) == 0) atomicMax((int*)(rmz + col), __float_as_int(cm));
      }
    }
  } else {
    #pragma unroll
    for (int mf = 0; mf < 4; mf++){
      #pragma unroll
      for (int r = 0; r < 4; r++){
        int row = m0 + wm * 64 + mf * 16 + (l >> 4) * 4 + r;
        #pragma unroll
        for (int nf = 0; nf < 4; nf++){
          int col = n0 + wn * 64 + nf * 16 + (l & 15);
          const float* bp = col < 512 ? bq : (col < 1024 ? bk : bv);
          float v = acc[mf][nf][r] + bp[col & 511];
          qkv[(size_t)row * 1536 + col] = f2bf(v);
        }
      }
    }
  }
}

// ---------------------------------------------------------------------------
// 128x128 bf16 MFMA GEMM, BK=32 2-phase dbuf (32KB LDS -> 4 blocks/CU).
// B transposed (N,K) row-major.
// MODE 2: +bias +extra -> f32        MODE 3: relu(+bias) -> bf16
// MODE 6: SPLIT-K x2 (z = k-half): raw acc -> outf + z*M*N (f32 partials)
template<int MODE>
__global__ __launch_bounds__(256) void gemm_bt(
    const unsigned short* __restrict__ A,
    const unsigned short* __restrict__ Bt,
    int M, int N, int K,
    const float* __restrict__ bias,
    const float* __restrict__ extra,
    float* __restrict__ outf,
    unsigned short* __restrict__ outb)
{
  int m0 = blockIdx.y * 128, n0 = blockIdx.x * 128;
  if (MODE == 6){                      // split-K: offset into the k-half
    int z = blockIdx.z;
    A    += (size_t)z * (K >> 1);
    Bt   += (size_t)z * (K >> 1);
    outf += (size_t)z * (size_t)M * N;
  }
  const int KL = (MODE == 6) ? (K >> 1) : K;
  const int tid = threadIdx.x, w = tid >> 6, l = tid & 63;
  const int wm = w >> 1, wn = w & 1;
  __shared__ unsigned short lA[2][128 * 32];
  __shared__ unsigned short lB[2][128 * 32];
  f32x4 acc[4][4];
  const f32x4 z4 = {0.f, 0.f, 0.f, 0.f};
  #pragma unroll
  for (int i = 0; i < 4; i++){
    #pragma unroll
    for (int j = 0; j < 4; j++) acc[i][j] = z4;
  }
  const int sc = l & 3;
  const int lg = l >> 4;

  #pragma unroll
  for (int j = 0; j < 2; j++){
    int row = j * 64 + w * 16 + (l >> 2);
    gload16(A + (size_t)(m0 + row) * K + ((sc ^ SWZ32(row)) << 3),
            &lA[0][0] + j * 2048 + w * 512);
    gload16(Bt + (size_t)(n0 + row) * K + ((sc ^ SWZ32(row)) << 3),
            &lB[0][0] + j * 2048 + w * 512);
  }
  __syncthreads();

  int cur = 0;
  for (int k0 = 0; k0 < KL; k0 += 32, cur ^= 1){
    if (k0 + 32 < KL){
      #pragma unroll
      for (int j = 0; j < 2; j++){
        int row = j * 64 + w * 16 + (l >> 2);
        gload16(A + (size_t)(m0 + row) * K + k0 + 32 + ((sc ^ SWZ32(row)) << 3),
                &lA[cur ^ 1][0] + j * 2048 + w * 512);
        gload16(Bt + (size_t)(n0 + row) * K + k0 + 32 + ((sc ^ SWZ32(row)) << 3),
                &lB[cur ^ 1][0] + j * 2048 + w * 512);
      }
    }
    bf16x8 af[4], bv[4];
    #pragma unroll
    for (int f = 0; f < 4; f++){
      int ra = wm * 64 + f * 16 + (l & 15);
      af[f] = *(const bf16x8*)((const char*)&lA[cur][0] + ra * 64 +
                ((lg ^ SWZ32(ra)) << 4));
      int rb = wn * 64 + f * 16 + (l & 15);
      bv[f] = *(const bf16x8*)((const char*)&lB[cur][0] + rb * 64 +
                ((lg ^ SWZ32(rb)) << 4));
    }
    #pragma unroll
    for (int mf = 0; mf < 4; mf++){
      #pragma unroll
      for (int nf = 0; nf < 4; nf++)
        acc[mf][nf] = mfma16(af[mf], bv[nf], acc[mf][nf]);
    }
    __syncthreads();
  }

  #pragma unroll
  for (int mf = 0; mf < 4; mf++){
    #pragma unroll
    for (int r = 0; r < 4; r++){
      int row = m0 + wm * 64 + mf * 16 + (l >> 4) * 4 + r;
      #pragma unroll
      for (int nf = 0; nf < 4; nf++){
        int col = n0 + wn * 64 + nf * 16 + (l & 15);
        if (MODE == 6){
          outf[(size_t)row * N + col] = acc[mf][nf][r];
        } else {
          float v = acc[mf][nf][r] + bias[col];
          if (MODE == 3) outb[(size_t)row * N + col] = f2bf(fmaxf(v, 0.f));
          if (MODE == 2)
            outf[(size_t)row * N + col] = v + extra[(size_t)row * N + col];
        }
      }
    }
  }
}

// ---------------------------------------------------------------------------
// flash attention, SWAPPED QK^T, FIXED-m exp2 softmax, QBLK=64 (R12-proven).
// grid (L/64, H, B) = 1024 blocks, block 256 (4 waves x 16 q-rows).
// LDS 40KB -> 4 blocks/CU.
__global__ __launch_bounds__(256, 4) void flash_attn(
    const unsigned short* __restrict__ qkv,
    const unsigned short* __restrict__ vT,
    const unsigned short* __restrict__ cdm,   // cd*LOG2E + 8
    const float* __restrict__ rmax,           // max_k of stored cdm
    unsigned short* __restrict__ y)
{
  const int b = blockIdx.z, h = blockIdx.y, q0 = blockIdx.x * 64;
  const int tid = threadIdx.x, w = tid >> 6, l = tid & 63;
  const int ql = l & 15, lg = l >> 4;
  __shared__ unsigned short QPs[64 * 64];    //  8KB: Q staging; reused as P
  __shared__ unsigned short Ks[2][64 * 64];  // 16KB dbuf
  __shared__ unsigned short Vs[2][64 * 64];  // 16KB dbuf

  const int srow = w * 8 + (l >> 3);
  const int sc = l & 7;
  const unsigned short* kbase = qkv + (size_t)b * Ll * 1536 + 512 + h * DHd;
  const unsigned short* vbase = vT + (size_t)(b * Hh + h) * DHd * Ll;

  // prologue: stage Q + tile 0 of K/V
  #pragma unroll
  for (int j = 0; j < 2; j++){
    int row = j * 32 + srow;
    gload16(qkv + (size_t)(b * Ll + q0 + row) * 1536 + h * DHd + ((sc ^ (row & 7)) << 3),
            QPs + j * 2048 + w * 512);
    gload16(kbase + (size_t)row * 1536 + ((sc ^ (row & 7)) << 3),
            &Ks[0][0] + j * 2048 + w * 512);
    gload16(vbase + (size_t)row * Ll + ((sc ^ (row & 7)) << 3),
            &Vs[0][0] + j * 2048 + w * 512);
  }

  const int qg = q0 + w * 16 + ql;                 // this lane's q-row
  const float rmx8 = rmax[b * Ll + qg] - 8.f;      // diag correction
  const unsigned short* cdrow = cdm + (size_t)(b * Ll + qg) * Ll;

  // register-prefetch cd bias for tile 0
  uint2 cdn[4];
  #pragma unroll
  for (int nf = 0; nf < 4; nf++)
    cdn[nf] = *(const uint2*)(cdrow + nf * 16 + lg * 4);

  f32x4 o[4];
  const f32x4 z4 = {0.f, 0.f, 0.f, 0.f};
  #pragma unroll
  for (int nf = 0; nf < 4; nf++) o[nf] = z4;
  float lsum = 0.f;

  __syncthreads();   // Q + tile 0 resident

  // hoist Q B-fragments (constant over k-loop); QPs region free afterwards
  bf16x8 qa[2];
  #pragma unroll
  for (int kk = 0; kk < 2; kk++){
    int ra = w * 16 + ql;
    qa[kk] = *(const bf16x8*)((const char*)QPs + ra * 128 +
               (((kk * 4 + lg) ^ (ql & 7)) << 4));
  }

  const int NT = Ll / 64;
  for (int t = 0; t < NT; ++t){
    const int k0 = t * 64;
    const int cur = t & 1;

    uint2 cdc[4];                       // this tile's bias (prefetched last tile)
    #pragma unroll
    for (int nf = 0; nf < 4; nf++) cdc[nf] = cdn[nf];

    if (t + 1 < NT){
      const int kn = k0 + 64;
      #pragma unroll
      for (int nf = 0; nf < 4; nf++)    // prefetch next tile's bias
        cdn[nf] = *(const uint2*)(cdrow + kn + nf * 16 + lg * 4);
      #pragma unroll
      for (int j = 0; j < 2; j++){      // stage next K/V (overlaps compute)
        int row = j * 32 + srow;
        gload16(kbase + (size_t)(kn + row) * 1536 + ((sc ^ (row & 7)) << 3),
                &Ks[cur ^ 1][0] + j * 2048 + w * 512);
        gload16(vbase + (size_t)row * Ll + kn + ((sc ^ (row & 7)) << 3),
                &Vs[cur ^ 1][0] + j * 2048 + w * 512);
      }
    }

    // S^T = K Q^T : lane gets q = w*16+ql, k = nf*16 + lg*4 + r
    f32x4 s[4];
    #pragma unroll
    for (int nf = 0; nf < 4; nf++){
      s[nf] = z4;
      #pragma unroll
      for (int kk = 0; kk < 2; kk++){
        int rb = nf * 16 + ql;
        bf16x8 kb = *(const bf16x8*)((const char*)Ks[cur] + rb * 128 +
                      (((kk * 4 + lg) ^ (ql & 7)) << 4));
        s[nf] = mfma16(kb, qa[kk], s[nf]);
      }
    }

    // ---- fixed-m softmax: p = 2^(qk*c - cdm'), no running max ----
    float sv[16];
    #pragma unroll
    for (int nf = 0; nf < 4; nf++){
      float c0 = __uint_as_float(cdc[nf].x << 16);
      float c1 = __uint_as_float(cdc[nf].x & 0xffff0000u);
      float c2 = __uint_as_float(cdc[nf].y << 16);
      float c3 = __uint_as_float(cdc[nf].y & 0xffff0000u);
      sv[nf * 4 + 0] = fmaf(s[nf][0], 0.125f * LOG2E, -c0);
      sv[nf * 4 + 1] = fmaf(s[nf][1], 0.125f * LOG2E, -c1);
      sv[nf * 4 + 2] = fmaf(s[nf][2], 0.125f * LOG2E, -c2);
      sv[nf * 4 + 3] = fmaf(s[nf][3], 0.125f * LOG2E, -c3);
    }
    if (k0 == q0){            // diagonal tile: subtract (rmax_stored - 8)
      #pragma unroll
      for (int nf = 0; nf < 4; nf++) if (nf == w){
        #pragma unroll
        for (int r = 0; r < 4; r++)
          if (lg * 4 + r == ql) sv[nf * 4 + r] -= rmx8;
      }
    }

    float p[16], ps = 0.f;
    #pragma unroll
    for (int i = 0; i < 16; i++){ p[i] = exp2_hw(sv[i]); ps += p[i]; }
    lsum += ps;                         // per-lane partial; reduce at end

    // P -> LDS (wave-private region of QPs), packed b64 per nf
    #pragma unroll
    for (int nf = 0; nf < 4; nf++){
      unsigned d0, d1;
      asm("v_cvt_pk_bf16_f32 %0, %1, %2" : "=v"(d0) : "v"(p[nf*4+0]), "v"(p[nf*4+1]));
      asm("v_cvt_pk_bf16_f32 %0, %1, %2" : "=v"(d1) : "v"(p[nf*4+2]), "v"(p[nf*4+3]));
      uint2 pk2; pk2.x = d0; pk2.y = d1;
      *(uint2*)((char*)QPs + w * 2048 + ql * 128 +
                ((nf * 32 + lg * 8) ^ ((ql & 7) << 4))) = pk2;
    }

    // PV: A = P (rows = q), B = V (cols = dh)
    bf16x8 pa[2];
    #pragma unroll
    for (int kk = 0; kk < 2; kk++)
      pa[kk] = *(const bf16x8*)((const char*)QPs + w * 2048 + ql * 128 +
                 ((((kk * 4 + lg)) ^ (ql & 7)) << 4));
    #pragma unroll
    for (int nf = 0; nf < 4; nf++){
      #pragma unroll
      for (int kk = 0; kk < 2; kk++){
        int rv = nf * 16 + ql;
        bf16x8 vb = *(const bf16x8*)((const char*)Vs[cur] + rv * 128 +
                      (((kk * 4 + lg) ^ (ql & 7)) << 4));
        o[nf] = mfma16(pa[kk], vb, o[nf]);
      }
    }
    __syncthreads();   // staged loads drained; buffers safe to swap
  }

  // epilogue: O rows are q = q0 + w*16 + lg*4 + r; reduce lsum across lg now
  float ltot = lsum;
  ltot += __shfl_xor(ltot, 16, 64);
  ltot += __shfl_xor(ltot, 32, 64);
  float lf[4];
  #pragma unroll
  for (int r = 0; r < 4; r++)
    lf[r] = __shfl(ltot, (l & 48) | (lg * 4 + r), 64);
  #pragma unroll
  for (int nf = 0; nf < 4; nf++){
    #pragma unroll
    for (int r = 0; r < 4; r++){
      int qo = q0 + w * 16 + lg * 4 + r;
      float v = o[nf][r] / lf[r];
      y[(size_t)(b * Ll + qo) * Dd + h * DHd + nf * 16 + ql] = f2bf(v);
    }
  }
}

// ---------------------------------------------------------------------------
// layernorm over D=512 -> bf16 only.  grid = B*L, block 256 (2 elems/thr)
__global__ __launch_bounds__(256) void ln_kernel(const float* __restrict__ in,
                                                 const float* __restrict__ g,
                                                 const float* __restrict__ bt,
                                                 unsigned short* __restrict__ outb){
  int row = blockIdx.x, tid = threadIdx.x;
  float2 v = ((const float2*)(in + (size_t)row * Dd))[tid];
  float s = v.x + v.y, s2 = v.x * v.x + v.y * v.y;
  #pragma unroll
  for (int t = 1; t < 64; t <<= 1){ s += __shfl_xor(s, t, 64); s2 += __shfl_xor(s2, t, 64); }
  __shared__ float red[8];
  if ((tid & 63) == 0){ red[tid >> 6] = s; red[4 + (tid >> 6)] = s2; }
  __syncthreads();
  float S  = red[0] + red[1] + red[2] + red[3];
  float S2 = red[4] + red[5] + red[6] + red[7];
  float mu = S * (1.f / 512.f);
  float var = fmaxf(S2 * (1.f / 512.f) - mu * mu, 0.f);
  float rs = rsqrtf(var + 1e-5f);
  int c = tid * 2;
  float o0 = (v.x - mu) * rs * g[c] + bt[c];
  float o1 = (v.y - mu) * rs * g[c + 1] + bt[c + 1];
  ((unsigned*)(outb + (size_t)row * Dd))[tid] =
      (unsigned)f2bf(o0) | ((unsigned)f2bf(o1) << 16);
}

// ---------------------------------------------------------------------------
// layernorm over (p0 + p1 + bias + extra_bf16): combines FFN2 split-K partials,
// adds the bf16 residual (LN1 output), then LN.  grid = B*L, block 256.
__global__ __launch_bounds__(256) void ln2p_kernel(
    const float* __restrict__ p01,              // [2][M][512] raw FFN2 partials
    const float* __restrict__ bias,
    const unsigned short* __restrict__ extra,   // residual, bf16 (LN1 out)
    const float* __restrict__ g, const float* __restrict__ bt,
    float* __restrict__ outf)
{
  int row = blockIdx.x, tid = threadIdx.x;
  float2 a0 = ((const float2*)(p01 + (size_t)row * Dd))[tid];
  float2 a1 = ((const float2*)(p01 + (size_t)Bb * Ll * Dd + (size_t)row * Dd))[tid];
  unsigned ex = ((const unsigned*)(extra + (size_t)row * Dd))[tid];
  float ex0 = __uint_as_float(ex << 16);
  float ex1 = __uint_as_float(ex & 0xffff0000u);
  int c = tid * 2;
  float vx = a0.x + a1.x + bias[c]     + ex0;
  float vy = a0.y + a1.y + bias[c + 1] + ex1;
  float s = vx + vy, s2 = vx * vx + vy * vy;
  #pragma unroll
  for (int t = 1; t < 64; t <<= 1){ s += __shfl_xor(s, t, 64); s2 += __shfl_xor(s2, t, 64); }
  __shared__ float red[8];
  if ((tid & 63) == 0){ red[tid >> 6] = s; red[4 + (tid >> 6)] = s2; }
  __syncthreads();
  float S  = red[0] + red[1] + red[2] + red[3];
  float S2 = red[4] + red[5] + red[6] + red[7];
  float mu = S * (1.f / 512.f);
  float var = fmaxf(S2 * (1.f / 512.f) - mu * mu, 0.f);
  float rs = rsqrtf(var + 1e-5f);
  float o0 = (vx - mu) * rs * g[c] + bt[c];
  float o1 = (vy - mu) * rs * g[c + 1] + bt[c + 1];
  float2 ov; ov.x = o0; ov.y = o1;
  ((float2*)(outf + (size_t)row * Dd))[tid] = ov;
}

// ---------------------------------------------------------------------------
extern "C" void kernel_launch(void* const* d_in, const int* in_sizes, int n_in,
                              void* d_out, int out_size, void* d_ws, size_t ws_size,
                              hipStream_t stream){
  const float* x     = (const float*)d_in[0];
  const float* nmask = (const float*)d_in[1];
  const float* wq = (const float*)d_in[2];  const float* bq = (const float*)d_in[3];
  const float* wk = (const float*)d_in[4];  const float* bk = (const float*)d_in[5];
  const float* wv = (const float*)d_in[6];  const float* bv = (const float*)d_in[7];
  const float* wo = (const float*)d_in[8];  const float* bo = (const float*)d_in[9];
  const float* ln1g = (const float*)d_in[10]; const float* ln1b = (const float*)d_in[11];
  const float* w1 = (const float*)d_in[12]; const float* b1 = (const float*)d_in[13];
  const float* w2 = (const float*)d_in[14]; const float* b2 = (const float*)d_in[15];
  const float* ln2g = (const float*)d_in[16]; const float* ln2b = (const float*)d_in[17];
  float* outp = (float*)d_out;
  char* ws = (char*)d_ws;

  // workspace layout (bytes)
  unsigned short* xbf   = (unsigned short*)(ws + 0);          //  8 MB
  float* sq   = (float*)(ws + 8388608);                       //  32 KB
  float* rmax = (float*)(ws + 8421376);                       //  32 KB
  unsigned short* wqkvT = (unsigned short*)(ws + 8454144);    //  1.5 MB (1536 x 512)
  unsigned short* woT   = (unsigned short*)(ws + 10027008);   //  512 KB
  unsigned short* w1T   = (unsigned short*)(ws + 10551296);   //  2 MB
  unsigned short* w2T   = (unsigned short*)(ws + 12648448);   //  2 MB
  unsigned short* cdm   = (unsigned short*)(ws + 14745600);   // 32 MB (later reused as h1)
  unsigned short* qkv   = (unsigned short*)(ws + 48300032);   // 24 MB (b,l,1536)
  unsigned short* vT    = (unsigned short*)(ws + 73465856);   //  8 MB
  unsigned short* yb    = (unsigned short*)(ws + 81854464);   //  8 MB
  float* res = (float*)(ws + 90243072);                       // 16 MB (resid1)
  // FFN2 split-K partials: 32 MB spanning [res, res+32MB) — res dead after LN1.
  float* p01 = res;
  unsigned short* h1  = cdm;    // reuse (cdist dead after attention)
  unsigned short* Xbf = qkv;    // reuse (qkv dead after attention); LN1 out bf16

  prep_all<<<3072 + Bb * Ll, 256, 0, stream>>>(x, wq, wk, wv, wo, w1, w2,
                                               xbf, sq, rmax, wqkvT, woT, w1T, w2T);

  // FUSED: triangular cdist (blocks 0..543) + QKV projection (544..1311)
  gemm_cq<<<1312, 256, 0, stream>>>(xbf, wqkvT, bq, bk, bv,
                                    cdm, qkv, sq, rmax, nmask);

  v_transpose<<<dim3(Ll / 64, Hh, Bb), 256, 0, stream>>>(qkv, vT);

  flash_attn<<<dim3(Ll / 64, Hh, Bb), 256, 0, stream>>>(qkv, vT, cdm, rmax, yb);

  // out projection + residual -> resid1 (f32)
  gemm_bt<2><<<dim3(4, 64, 1), 256, 0, stream>>>(yb, woT, Bb * Ll, Dd, Dd,
      bo, x, res, nullptr);

  // LN1 -> bf16 only (residual for LN2 is read back as bf16)
  ln_kernel<<<Bb * Ll, 256, 0, stream>>>(res, ln1g, ln1b, Xbf);

  // FFN
  gemm_bt<3><<<dim3(16, 64, 1), 256, 0, stream>>>(Xbf, w1T, Bb * Ll, 4 * Dd, Dd,
      b1, nullptr, nullptr, h1);
  // FFN2 split-K x2 -> raw f32 partials in p01 (p0 at 0, p1 at +M*N)
  gemm_bt<6><<<dim3(4, 64, 2), 256, 0, stream>>>(h1, w2T, Bb * Ll, Dd, 4 * Dd,
      nullptr, nullptr, p01, nullptr);

  ln2p_kernel<<<Bb * Ll, 256, 0, stream>>>(p01, b2, Xbf, ln2g, ln2b, outp);
}

// Round 14
// 227.389 us; speedup vs baseline: 1.0794x; 1.0794x over previous
//
#include <hip/hip_runtime.h>
#include <stdint.h>

#define GAS __attribute__((address_space(1)))
#define LAS __attribute__((address_space(3)))

typedef __attribute__((ext_vector_type(8))) __bf16 bf16x8;
typedef __attribute__((ext_vector_type(4))) float f32x4;

static constexpr int Bb = 4, Ll = 2048, Dd = 512, Hh = 8, DHd = 64;
static constexpr float LOG2E = 1.4426950408889634f;

__device__ __forceinline__ unsigned short f2bf(float f){
  unsigned u = __float_as_uint(f);
  u += 0x7fffu + ((u >> 16) & 1u);           // round-to-nearest-even
  return (unsigned short)(u >> 16);
}
__device__ __forceinline__ void gload16(const void* g, void* l){
  __builtin_amdgcn_global_load_lds((const GAS void*)g, (LAS void*)l, 16, 0, 0);
}
__device__ __forceinline__ f32x4 mfma16(bf16x8 a, bf16x8 b, f32x4 c){
  return __builtin_amdgcn_mfma_f32_16x16x32_bf16(a, b, c, 0, 0, 0);
}
__device__ __forceinline__ float exp2_hw(float x){   // v_exp_f32 = 2^x
  float r; asm("v_exp_f32 %0, %1" : "=v"(r) : "v"(x)); return r;
}

// ---------------------------------------------------------------------------
// fused prep: blocks [0,3072) = weight transposes (f32 (R,C) -> bf16 (C,R));
// blocks [3072, 3072+8192) = per-row sum-of-squares + x f32->bf16 cast + rmax=0.
__global__ __launch_bounds__(256) void prep_all(
    const float* __restrict__ x,
    const float* __restrict__ wq, const float* __restrict__ wk,
    const float* __restrict__ wv, const float* __restrict__ wo,
    const float* __restrict__ w1, const float* __restrict__ w2,
    unsigned short* __restrict__ xbf, float* __restrict__ sq,
    float* __restrict__ rmax,
    unsigned short* __restrict__ wqkvT, unsigned short* __restrict__ woT,
    unsigned short* __restrict__ w1T, unsigned short* __restrict__ w2T)
{
  __shared__ float t[32][33];
  __shared__ float red[4];
  int bid = blockIdx.x;
  if (bid >= 3072){
    // ---- sumsq + cast + rmax zero ----
    int row = bid - 3072, tid = threadIdx.x;
    float2 v = ((const float2*)(x + (size_t)row * Dd))[tid];
    ((unsigned*)(xbf + (size_t)row * Dd))[tid] =
        (unsigned)f2bf(v.x) | ((unsigned)f2bf(v.y) << 16);
    float s2 = v.x * v.x + v.y * v.y;
    #pragma unroll
    for (int s = 1; s < 64; s <<= 1) s2 += __shfl_xor(s2, s, 64);
    if ((tid & 63) == 0) red[tid >> 6] = s2;
    __syncthreads();
    if (tid == 0){
      sq[row] = red[0] + red[1] + red[2] + red[3];
      rmax[row] = 0.f;
    }
    return;
  }
  // ---- weight transpose ----
  const float* in; unsigned short* out; int R, C, bx, by;
  if (bid < 1024){
    int s = bid >> 8, tt = bid & 255;
    in  = s == 0 ? wq : s == 1 ? wk : s == 2 ? wv : wo;
    out = s == 3 ? woT : wqkvT + s * 512 * 512;
    R = 512; C = 512; bx = tt & 15; by = tt >> 4;
  } else if (bid < 2048){
    int tt = bid - 1024; in = w1; out = w1T; R = 512; C = 2048; bx = tt & 63; by = tt >> 6;
  } else {
    int tt = bid - 2048; in = w2; out = w2T; R = 2048; C = 512; bx = tt & 15; by = tt >> 4;
  }
  int tx = threadIdx.x & 31, ty = threadIdx.x >> 5;
  int c0 = bx * 32, r0 = by * 32;
  #pragma unroll
  for (int j = 0; j < 32; j += 8) t[ty + j][tx] = in[(size_t)(r0 + ty + j) * C + c0 + tx];
  __syncthreads();
  #pragma unroll
  for (int j = 0; j < 32; j += 8) out[(size_t)(c0 + ty + j) * R + r0 + tx] = f2bf(t[tx][ty + j]);
}

// ---------------------------------------------------------------------------
// v slice of fused qkv (b,l,1536) -> vT (b,h,dh,l) bf16. grid (L/64,H,B), blk 256
__global__ __launch_bounds__(256) void v_transpose(const unsigned short* __restrict__ qkv,
                                                   unsigned short* __restrict__ vT){
  int b = blockIdx.z, h = blockIdx.y, l0 = blockIdx.x * 64;
  int tid = threadIdx.x;
  __shared__ unsigned short t[64 * 64];
  #pragma unroll
  for (int it = 0; it < 2; ++it){
    int row = tid >> 2;                 // local l
    int c = (tid & 3) + it * 4;         // 16B granule (8 dh)
    uint4 d = *(const uint4*)(qkv + (size_t)(b * Ll + l0 + row) * 1536 + 1024 + h * DHd + c * 8);
    *(uint4*)((char*)t + row * 128 + ((c ^ (row & 7)) << 4)) = d;
  }
  __syncthreads();
  #pragma unroll
  for (int it = 0; it < 2; ++it){
    int dh = tid >> 2;
    int c2 = (tid & 3) + it * 4;        // granule along l (8 l-values)
    unsigned pk[4];
    #pragma unroll
    for (int p = 0; p < 4; ++p){
      unsigned short e0, e1;
      {
        int ll = c2 * 8 + p * 2;
        e0 = *(const unsigned short*)((const char*)t + ll * 128 +
              ((((dh >> 3) ^ (ll & 7))) << 4) + ((dh & 7) << 1));
        ll = c2 * 8 + p * 2 + 1;
        e1 = *(const unsigned short*)((const char*)t + ll * 128 +
              ((((dh >> 3) ^ (ll & 7))) << 4) + ((dh & 7) << 1));
      }
      pk[p] = (unsigned)e0 | ((unsigned)e1 << 16);
    }
    uint4 o; o.x = pk[0]; o.y = pk[1]; o.z = pk[2]; o.w = pk[3];
    *(uint4*)(vT + ((size_t)(b * Hh + h) * DHd + dh) * Ll + l0 + c2 * 8) = o;
  }
}

// ---------------------------------------------------------------------------
// FUSED cdist + QKV GEMM (both K=512, independent, share the MFMA main loop).
// 128x128 tile, BK=64, 2-phase LDS dbuf (R12-proven operating point).
// blocks [0,544): triangular cdist (136 upper-tri tiles x 4 batches);
// blocks [544,1312): fused QKV projection (12 x 64 tiles), 3-way bias.
__global__ __launch_bounds__(256) void gemm_cq(
    const unsigned short* __restrict__ xbf,
    const unsigned short* __restrict__ wqkvT,
    const float* __restrict__ bq, const float* __restrict__ bk,
    const float* __restrict__ bv,
    unsigned short* __restrict__ cdm, unsigned short* __restrict__ qkv,
    const float* __restrict__ sq, float* __restrict__ rmax,
    const float* __restrict__ mask)
{
  const int bid = blockIdx.x;
  const bool isc = bid < 544;
  const unsigned short *Ap, *Bp;
  int m0, n0, bxx = 0, byy = 0, zb = 0;
  if (isc){
    zb = bid / 136;
    int tt = bid - zb * 136, byv = 0;
    while (tt >= 16 - byv){ tt -= 16 - byv; byv++; }
    byy = byv; bxx = byv + tt;
    m0 = byy * 128; n0 = bxx * 128;
    Ap = xbf + (size_t)zb * Ll * Dd; Bp = Ap;
  } else {
    int t = bid - 544;
    int bx = t % 12, by = t / 12;
    m0 = by * 128; n0 = bx * 128;
    Ap = xbf; Bp = wqkvT;
  }
  const int tid = threadIdx.x, w = tid >> 6, l = tid & 63;
  const int wm = w >> 1, wn = w & 1;
  __shared__ unsigned short lA[2][128 * 64];
  __shared__ unsigned short lB[2][128 * 64];
  f32x4 acc[4][4];
  const f32x4 z4 = {0.f, 0.f, 0.f, 0.f};
  #pragma unroll
  for (int i = 0; i < 4; i++){
    #pragma unroll
    for (int j = 0; j < 4; j++) acc[i][j] = z4;
  }
  const int srow = w * 8 + (l >> 3);
  const int sc = l & 7;

  // prologue: stage k-tile 0 (K = 512 for both modes)
  #pragma unroll
  for (int j = 0; j < 4; j++){
    int row = j * 32 + srow;
    gload16(Ap + (size_t)(m0 + row) * Dd + ((sc ^ (row & 7)) << 3),
            &lA[0][0] + j * 2048 + w * 512);
    gload16(Bp + (size_t)(n0 + row) * Dd + ((sc ^ (row & 7)) << 3),
            &lB[0][0] + j * 2048 + w * 512);
  }
  __syncthreads();

  int cur = 0;
  for (int k0 = 0; k0 < Dd; k0 += 64, cur ^= 1){
    if (k0 + 64 < Dd){
      #pragma unroll
      for (int j = 0; j < 4; j++){
        int row = j * 32 + srow;
        gload16(Ap + (size_t)(m0 + row) * Dd + k0 + 64 + ((sc ^ (row & 7)) << 3),
                &lA[cur ^ 1][0] + j * 2048 + w * 512);
        gload16(Bp + (size_t)(n0 + row) * Dd + k0 + 64 + ((sc ^ (row & 7)) << 3),
                &lB[cur ^ 1][0] + j * 2048 + w * 512);
      }
    }
    bf16x8 af[4][2], bvv[4][2];
    #pragma unroll
    for (int kk = 0; kk < 2; kk++){
      #pragma unroll
      for (int f = 0; f < 4; f++){
        int ra = wm * 64 + f * 16 + (l & 15);
        af[f][kk] = *(const bf16x8*)((const char*)&lA[cur][0] + ra * 128 +
                      (((kk * 4 + (l >> 4)) ^ (ra & 7)) << 4));
        int rb = wn * 64 + f * 16 + (l & 15);
        bvv[f][kk] = *(const bf16x8*)((const char*)&lB[cur][0] + rb * 128 +
                      (((kk * 4 + (l >> 4)) ^ (rb & 7)) << 4));
      }
    }
    #pragma unroll
    for (int mf = 0; mf < 4; mf++){
      #pragma unroll
      for (int nf = 0; nf < 4; nf++){
        #pragma unroll
        for (int kk = 0; kk < 2; kk++)
          acc[mf][nf] = mfma16(af[mf][kk], bvv[nf][kk], acc[mf][nf]);
      }
    }
    __syncthreads();
  }

  if (isc){
    unsigned short* outb = cdm + (size_t)zb * Ll * Ll;
    const float* sqz = sq + zb * Ll;
    const float* mkz = mask + zb * Ll;
    float* rmz = rmax + zb * Ll;
    float sqc[4], mkc[4];
    #pragma unroll
    for (int nf = 0; nf < 4; nf++){
      int col = n0 + wn * 64 + nf * 16 + (l & 15);
      sqc[nf] = sqz[col]; mkc[nf] = mkz[col];
    }
    #pragma unroll
    for (int mf = 0; mf < 4; mf++){
      #pragma unroll
      for (int r = 0; r < 4; r++){
        int row = m0 + wm * 64 + mf * 16 + (l >> 4) * 4 + r;
        float sqi = sqz[row], mi = mkz[row];
        #pragma unroll
        for (int nf = 0; nf < 4; nf++){
          float d2 = sqi + sqc[nf] - 2.f * acc[mf][nf][r];
          acc[mf][nf][r] = sqrtf(fmaxf(d2, 0.f)) * (mi * mkc[nf]) * LOG2E + 8.f;
        }
      }
    }
    #pragma unroll
    for (int mf = 0; mf < 4; mf++){
      #pragma unroll
      for (int r = 0; r < 4; r++){
        int row = m0 + wm * 64 + mf * 16 + (l >> 4) * 4 + r;
        float rm = 0.f;
        #pragma unroll
        for (int nf = 0; nf < 4; nf++){
          int col = n0 + wn * 64 + nf * 16 + (l & 15);
          outb[(size_t)row * Ll + col] = f2bf(acc[mf][nf][r]);
          rm = fmaxf(rm, acc[mf][nf][r]);
        }
        #pragma unroll
        for (int t = 1; t < 16; t <<= 1) rm = fmaxf(rm, __shfl_xor(rm, t, 64));
        if ((l & 15) == 0) atomicMax((int*)(rmz + row), __float_as_int(rm));
      }
    }
    if (bxx != byy){
      #pragma unroll
      for (int nf = 0; nf < 4; nf++){
        int col = n0 + wn * 64 + nf * 16 + (l & 15);
        float cm = 0.f;
        #pragma unroll
        for (int mf = 0; mf < 4; mf++){
          uint2 pk2;
          pk2.x = (unsigned)f2bf(acc[mf][nf][0]) | ((unsigned)f2bf(acc[mf][nf][1]) << 16);
          pk2.y = (unsigned)f2bf(acc[mf][nf][2]) | ((unsigned)f2bf(acc[mf][nf][3]) << 16);
          int rowb = m0 + wm * 64 + mf * 16 + (l >> 4) * 4;
          *(uint2*)(outb + (size_t)col * Ll + rowb) = pk2;
          cm = fmaxf(cm, fmaxf(fmaxf(acc[mf][nf][0], acc[mf][nf][1]),
                               fmaxf(acc[mf][nf][2], acc[mf][nf][3])));
        }
        cm = fmaxf(cm, __shfl_xor(cm, 16, 64));
        cm = fmaxf(cm, __shfl_xor(cm, 32, 64));
        if ((l >> 4) == 0) atomicMax((int*)(rmz + col), __float_as_int(cm));
      }
    }
  } else {
    #pragma unroll
    for (int mf = 0; mf < 4; mf++){
      #pragma unroll
      for (int r = 0; r < 4; r++){
        int row = m0 + wm * 64 + mf * 16 + (l >> 4) * 4 + r;
        #pragma unroll
        for (int nf = 0; nf < 4; nf++){
          int col = n0 + wn * 64 + nf * 16 + (l & 15);
          const float* bp = col < 512 ? bq : (col < 1024 ? bk : bv);
          float v = acc[mf][nf][r] + bp[col & 511];
          qkv[(size_t)row * 1536 + col] = f2bf(v);
        }
      }
    }
  }
}

// ---------------------------------------------------------------------------
// 128x128x64 bf16 MFMA GEMM, B transposed (N,K) row-major, 2-phase LDS dbuf.
// MODE 2: +bias +extra -> f32        MODE 3: relu(+bias) -> bf16
// MODE 6: SPLIT-K x2 (z = k-half): raw acc -> outf + z*M*N (f32 partials)
template<int MODE>
__global__ __launch_bounds__(256) void gemm_bt(
    const unsigned short* __restrict__ A,
    const unsigned short* __restrict__ Bt,
    int M, int N, int K,
    const float* __restrict__ bias,
    const float* __restrict__ extra,
    float* __restrict__ outf,
    unsigned short* __restrict__ outb)
{
  int m0 = blockIdx.y * 128, n0 = blockIdx.x * 128;
  if (MODE == 6){                      // split-K: offset into the k-half
    int z = blockIdx.z;
    A    += (size_t)z * (K >> 1);
    Bt   += (size_t)z * (K >> 1);
    outf += (size_t)z * (size_t)M * N;
  }
  const int KL = (MODE == 6) ? (K >> 1) : K;
  const int tid = threadIdx.x, w = tid >> 6, l = tid & 63;
  const int wm = w >> 1, wn = w & 1;
  __shared__ unsigned short lA[2][128 * 64];
  __shared__ unsigned short lB[2][128 * 64];
  f32x4 acc[4][4];
  const f32x4 z4 = {0.f, 0.f, 0.f, 0.f};
  #pragma unroll
  for (int i = 0; i < 4; i++){
    #pragma unroll
    for (int j = 0; j < 4; j++) acc[i][j] = z4;
  }
  const int srow = w * 8 + (l >> 3);
  const int sc = l & 7;

  #pragma unroll
  for (int j = 0; j < 4; j++){
    int row = j * 32 + srow;
    gload16(A + (size_t)(m0 + row) * K + ((sc ^ (row & 7)) << 3),
            &lA[0][0] + j * 2048 + w * 512);
    gload16(Bt + (size_t)(n0 + row) * K + ((sc ^ (row & 7)) << 3),
            &lB[0][0] + j * 2048 + w * 512);
  }
  __syncthreads();

  int cur = 0;
  for (int k0 = 0; k0 < KL; k0 += 64, cur ^= 1){
    if (k0 + 64 < KL){
      #pragma unroll
      for (int j = 0; j < 4; j++){
        int row = j * 32 + srow;
        gload16(A + (size_t)(m0 + row) * K + k0 + 64 + ((sc ^ (row & 7)) << 3),
                &lA[cur ^ 1][0] + j * 2048 + w * 512);
        gload16(Bt + (size_t)(n0 + row) * K + k0 + 64 + ((sc ^ (row & 7)) << 3),
                &lB[cur ^ 1][0] + j * 2048 + w * 512);
      }
    }
    bf16x8 af[4][2], bv[4][2];
    #pragma unroll
    for (int kk = 0; kk < 2; kk++){
      #pragma unroll
      for (int f = 0; f < 4; f++){
        int ra = wm * 64 + f * 16 + (l & 15);
        af[f][kk] = *(const bf16x8*)((const char*)&lA[cur][0] + ra * 128 +
                      (((kk * 4 + (l >> 4)) ^ (ra & 7)) << 4));
        int rb = wn * 64 + f * 16 + (l & 15);
        bv[f][kk] = *(const bf16x8*)((const char*)&lB[cur][0] + rb * 128 +
                      (((kk * 4 + (l >> 4)) ^ (rb & 7)) << 4));
      }
    }
    #pragma unroll
    for (int mf = 0; mf < 4; mf++){
      #pragma unroll
      for (int nf = 0; nf < 4; nf++){
        #pragma unroll
        for (int kk = 0; kk < 2; kk++)
          acc[mf][nf] = mfma16(af[mf][kk], bv[nf][kk], acc[mf][nf]);
      }
    }
    __syncthreads();
  }

  #pragma unroll
  for (int mf = 0; mf < 4; mf++){
    #pragma unroll
    for (int r = 0; r < 4; r++){
      int row = m0 + wm * 64 + mf * 16 + (l >> 4) * 4 + r;
      #pragma unroll
      for (int nf = 0; nf < 4; nf++){
        int col = n0 + wn * 64 + nf * 16 + (l & 15);
        if (MODE == 6){
          outf[(size_t)row * N + col] = acc[mf][nf][r];
        } else {
          float v = acc[mf][nf][r] + bias[col];
          if (MODE == 3) outb[(size_t)row * N + col] = f2bf(fmaxf(v, 0.f));
          if (MODE == 2)
            outf[(size_t)row * N + col] = v + extra[(size_t)row * N + col];
        }
      }
    }
  }
}

// ---------------------------------------------------------------------------
// flash attention, SWAPPED QK^T, FIXED-m exp2 softmax, QBLK=64 (R12-proven).
// grid (L/64, H, B) = 1024 blocks, block 256 (4 waves x 16 q-rows).
// LDS 40KB -> 4 blocks/CU.
__global__ __launch_bounds__(256, 4) void flash_attn(
    const unsigned short* __restrict__ qkv,
    const unsigned short* __restrict__ vT,
    const unsigned short* __restrict__ cdm,   // cd*LOG2E + 8
    const float* __restrict__ rmax,           // max_k of stored cdm
    unsigned short* __restrict__ y)
{
  const int b = blockIdx.z, h = blockIdx.y, q0 = blockIdx.x * 64;
  const int tid = threadIdx.x, w = tid >> 6, l = tid & 63;
  const int ql = l & 15, lg = l >> 4;
  __shared__ unsigned short QPs[64 * 64];    //  8KB: Q staging; reused as P
  __shared__ unsigned short Ks[2][64 * 64];  // 16KB dbuf
  __shared__ unsigned short Vs[2][64 * 64];  // 16KB dbuf

  const int srow = w * 8 + (l >> 3);
  const int sc = l & 7;
  const unsigned short* kbase = qkv + (size_t)b * Ll * 1536 + 512 + h * DHd;
  const unsigned short* vbase = vT + (size_t)(b * Hh + h) * DHd * Ll;

  // prologue: stage Q + tile 0 of K/V
  #pragma unroll
  for (int j = 0; j < 2; j++){
    int row = j * 32 + srow;
    gload16(qkv + (size_t)(b * Ll + q0 + row) * 1536 + h * DHd + ((sc ^ (row & 7)) << 3),
            QPs + j * 2048 + w * 512);
    gload16(kbase + (size_t)row * 1536 + ((sc ^ (row & 7)) << 3),
            &Ks[0][0] + j * 2048 + w * 512);
    gload16(vbase + (size_t)row * Ll + ((sc ^ (row & 7)) << 3),
            &Vs[0][0] + j * 2048 + w * 512);
  }

  const int qg = q0 + w * 16 + ql;                 // this lane's q-row
  const float rmx8 = rmax[b * Ll + qg] - 8.f;      // diag correction
  const unsigned short* cdrow = cdm + (size_t)(b * Ll + qg) * Ll;

  // register-prefetch cd bias for tile 0
  uint2 cdn[4];
  #pragma unroll
  for (int nf = 0; nf < 4; nf++)
    cdn[nf] = *(const uint2*)(cdrow + nf * 16 + lg * 4);

  f32x4 o[4];
  const f32x4 z4 = {0.f, 0.f, 0.f, 0.f};
  #pragma unroll
  for (int nf = 0; nf < 4; nf++) o[nf] = z4;
  float lsum = 0.f;

  __syncthreads();   // Q + tile 0 resident

  // hoist Q B-fragments (constant over k-loop); QPs region free afterwards
  bf16x8 qa[2];
  #pragma unroll
  for (int kk = 0; kk < 2; kk++){
    int ra = w * 16 + ql;
    qa[kk] = *(const bf16x8*)((const char*)QPs + ra * 128 +
               (((kk * 4 + lg) ^ (ql & 7)) << 4));
  }

  const int NT = Ll / 64;
  for (int t = 0; t < NT; ++t){
    const int k0 = t * 64;
    const int cur = t & 1;

    uint2 cdc[4];                       // this tile's bias (prefetched last tile)
    #pragma unroll
    for (int nf = 0; nf < 4; nf++) cdc[nf] = cdn[nf];

    if (t + 1 < NT){
      const int kn = k0 + 64;
      #pragma unroll
      for (int nf = 0; nf < 4; nf++)    // prefetch next tile's bias
        cdn[nf] = *(const uint2*)(cdrow + kn + nf * 16 + lg * 4);
      #pragma unroll
      for (int j = 0; j < 2; j++){      // stage next K/V (overlaps compute)
        int row = j * 32 + srow;
        gload16(kbase + (size_t)(kn + row) * 1536 + ((sc ^ (row & 7)) << 3),
                &Ks[cur ^ 1][0] + j * 2048 + w * 512);
        gload16(vbase + (size_t)row * Ll + kn + ((sc ^ (row & 7)) << 3),
                &Vs[cur ^ 1][0] + j * 2048 + w * 512);
      }
    }

    // S^T = K Q^T : lane gets q = w*16+ql, k = nf*16 + lg*4 + r
    f32x4 s[4];
    #pragma unroll
    for (int nf = 0; nf < 4; nf++){
      s[nf] = z4;
      #pragma unroll
      for (int kk = 0; kk < 2; kk++){
        int rb = nf * 16 + ql;
        bf16x8 kb = *(const bf16x8*)((const char*)Ks[cur] + rb * 128 +
                      (((kk * 4 + lg) ^ (ql & 7)) << 4));
        s[nf] = mfma16(kb, qa[kk], s[nf]);
      }
    }

    // ---- fixed-m softmax: p = 2^(qk*c - cdm'), no running max ----
    float sv[16];
    #pragma unroll
    for (int nf = 0; nf < 4; nf++){
      float c0 = __uint_as_float(cdc[nf].x << 16);
      float c1 = __uint_as_float(cdc[nf].x & 0xffff0000u);
      float c2 = __uint_as_float(cdc[nf].y << 16);
      float c3 = __uint_as_float(cdc[nf].y & 0xffff0000u);
      sv[nf * 4 + 0] = fmaf(s[nf][0], 0.125f * LOG2E, -c0);
      sv[nf * 4 + 1] = fmaf(s[nf][1], 0.125f * LOG2E, -c1);
      sv[nf * 4 + 2] = fmaf(s[nf][2], 0.125f * LOG2E, -c2);
      sv[nf * 4 + 3] = fmaf(s[nf][3], 0.125f * LOG2E, -c3);
    }
    if (k0 == q0){            // diagonal tile: subtract (rmax_stored - 8)
      #pragma unroll
      for (int nf = 0; nf < 4; nf++) if (nf == w){
        #pragma unroll
        for (int r = 0; r < 4; r++)
          if (lg * 4 + r == ql) sv[nf * 4 + r] -= rmx8;
      }
    }

    float p[16], ps = 0.f;
    #pragma unroll
    for (int i = 0; i < 16; i++){ p[i] = exp2_hw(sv[i]); ps += p[i]; }
    lsum += ps;                         // per-lane partial; reduce at end

    // P -> LDS (wave-private region of QPs), packed b64 per nf
    #pragma unroll
    for (int nf = 0; nf < 4; nf++){
      unsigned d0, d1;
      asm("v_cvt_pk_bf16_f32 %0, %1, %2" : "=v"(d0) : "v"(p[nf*4+0]), "v"(p[nf*4+1]));
      asm("v_cvt_pk_bf16_f32 %0, %1, %2" : "=v"(d1) : "v"(p[nf*4+2]), "v"(p[nf*4+3]));
      uint2 pk2; pk2.x = d0; pk2.y = d1;
      *(uint2*)((char*)QPs + w * 2048 + ql * 128 +
                ((nf * 32 + lg * 8) ^ ((ql & 7) << 4))) = pk2;
    }

    // PV: A = P (rows = q), B = V (cols = dh)
    bf16x8 pa[2];
    #pragma unroll
    for (int kk = 0; kk < 2; kk++)
      pa[kk] = *(const bf16x8*)((const char*)QPs + w * 2048 + ql * 128 +
                 ((((kk * 4 + lg)) ^ (ql & 7)) << 4));
    #pragma unroll
    for (int nf = 0; nf < 4; nf++){
      #pragma unroll
      for (int kk = 0; kk < 2; kk++){
        int rv = nf * 16 + ql;
        bf16x8 vb = *(const bf16x8*)((const char*)Vs[cur] + rv * 128 +
                      (((kk * 4 + lg) ^ (ql & 7)) << 4));
        o[nf] = mfma16(pa[kk], vb, o[nf]);
      }
    }
    __syncthreads();   // staged loads drained; buffers safe to swap
  }

  // epilogue: O rows are q = q0 + w*16 + lg*4 + r; reduce lsum across lg now
  float ltot = lsum;
  ltot += __shfl_xor(ltot, 16, 64);
  ltot += __shfl_xor(ltot, 32, 64);
  float lf[4];
  #pragma unroll
  for (int r = 0; r < 4; r++)
    lf[r] = __shfl(ltot, (l & 48) | (lg * 4 + r), 64);
  #pragma unroll
  for (int nf = 0; nf < 4; nf++){
    #pragma unroll
    for (int r = 0; r < 4; r++){
      int qo = q0 + w * 16 + lg * 4 + r;
      float v = o[nf][r] / lf[r];
      y[(size_t)(b * Ll + qo) * Dd + h * DHd + nf * 16 + ql] = f2bf(v);
    }
  }
}

// ---------------------------------------------------------------------------
// layernorm over D=512 -> bf16 only.  grid = B*L, block 256 (2 elems/thr)
__global__ __launch_bounds__(256) void ln_kernel(const float* __restrict__ in,
                                                 const float* __restrict__ g,
                                                 const float* __restrict__ bt,
                                                 unsigned short* __restrict__ outb){
  int row = blockIdx.x, tid = threadIdx.x;
  float2 v = ((const float2*)(in + (size_t)row * Dd))[tid];
  float s = v.x + v.y, s2 = v.x * v.x + v.y * v.y;
  #pragma unroll
  for (int t = 1; t < 64; t <<= 1){ s += __shfl_xor(s, t, 64); s2 += __shfl_xor(s2, t, 64); }
  __shared__ float red[8];
  if ((tid & 63) == 0){ red[tid >> 6] = s; red[4 + (tid >> 6)] = s2; }
  __syncthreads();
  float S  = red[0] + red[1] + red[2] + red[3];
  float S2 = red[4] + red[5] + red[6] + red[7];
  float mu = S * (1.f / 512.f);
  float var = fmaxf(S2 * (1.f / 512.f) - mu * mu, 0.f);
  float rs = rsqrtf(var + 1e-5f);
  int c = tid * 2;
  float o0 = (v.x - mu) * rs * g[c] + bt[c];
  float o1 = (v.y - mu) * rs * g[c + 1] + bt[c + 1];
  ((unsigned*)(outb + (size_t)row * Dd))[tid] =
      (unsigned)f2bf(o0) | ((unsigned)f2bf(o1) << 16);
}

// ---------------------------------------------------------------------------
// layernorm over (p0 + p1 + bias + extra_bf16): combines FFN2 split-K partials,
// adds the bf16 residual (LN1 output), then LN.  grid = B*L, block 256.
__global__ __launch_bounds__(256) void ln2p_kernel(
    const float* __restrict__ p01,              // [2][M][512] raw FFN2 partials
    const float* __restrict__ bias,
    const unsigned short* __restrict__ extra,   // residual, bf16 (LN1 out)
    const float* __restrict__ g, const float* __restrict__ bt,
    float* __restrict__ outf)
{
  int row = blockIdx.x, tid = threadIdx.x;
  float2 a0 = ((const float2*)(p01 + (size_t)row * Dd))[tid];
  float2 a1 = ((const float2*)(p01 + (size_t)Bb * Ll * Dd + (size_t)row * Dd))[tid];
  unsigned ex = ((const unsigned*)(extra + (size_t)row * Dd))[tid];
  float ex0 = __uint_as_float(ex << 16);
  float ex1 = __uint_as_float(ex & 0xffff0000u);
  int c = tid * 2;
  float vx = a0.x + a1.x + bias[c]     + ex0;
  float vy = a0.y + a1.y + bias[c + 1] + ex1;
  float s = vx + vy, s2 = vx * vx + vy * vy;
  #pragma unroll
  for (int t = 1; t < 64; t <<= 1){ s += __shfl_xor(s, t, 64); s2 += __shfl_xor(s2, t, 64); }
  __shared__ float red[8];
  if ((tid & 63) == 0){ red[tid >> 6] = s; red[4 + (tid >> 6)] = s2; }
  __syncthreads();
  float S  = red[0] + red[1] + red[2] + red[3];
  float S2 = red[4] + red[5] + red[6] + red[7];
  float mu = S * (1.f / 512.f);
  float var = fmaxf(S2 * (1.f / 512.f) - mu * mu, 0.f);
  float rs = rsqrtf(var + 1e-5f);
  float o0 = (vx - mu) * rs * g[c] + bt[c];
  float o1 = (vy - mu) * rs * g[c + 1] + bt[c + 1];
  float2 ov; ov.x = o0; ov.y = o1;
  ((float2*)(outf + (size_t)row * Dd))[tid] = ov;
}

// ---------------------------------------------------------------------------
extern "C" void kernel_launch(void* const* d_in, const int* in_sizes, int n_in,
                              void* d_out, int out_size, void* d_ws, size_t ws_size,
                              hipStream_t stream){
  const float* x     = (const float*)d_in[0];
  const float* nmask = (const float*)d_in[1];
  const float* wq = (const float*)d_in[2];  const float* bq = (const float*)d_in[3];
  const float* wk = (const float*)d_in[4];  const float* bk = (const float*)d_in[5];
  const float* wv = (const float*)d_in[6];  const float* bv = (const float*)d_in[7];
  const float* wo = (const float*)d_in[8];  const float* bo = (const float*)d_in[9];
  const float* ln1g = (const float*)d_in[10]; const float* ln1b = (const float*)d_in[11];
  const float* w1 = (const float*)d_in[12]; const float* b1 = (const float*)d_in[13];
  const float* w2 = (const float*)d_in[14]; const float* b2 = (const float*)d_in[15];
  const float* ln2g = (const float*)d_in[16]; const float* ln2b = (const float*)d_in[17];
  float* outp = (float*)d_out;
  char* ws = (char*)d_ws;

  // workspace layout (bytes)
  unsigned short* xbf   = (unsigned short*)(ws + 0);          //  8 MB
  float* sq   = (float*)(ws + 8388608);                       //  32 KB
  float* rmax = (float*)(ws + 8421376);                       //  32 KB
  unsigned short* wqkvT = (unsigned short*)(ws + 8454144);    //  1.5 MB (1536 x 512)
  unsigned short* woT   = (unsigned short*)(ws + 10027008);   //  512 KB
  unsigned short* w1T   = (unsigned short*)(ws + 10551296);   //  2 MB
  unsigned short* w2T   = (unsigned short*)(ws + 12648448);   //  2 MB
  unsigned short* cdm   = (unsigned short*)(ws + 14745600);   // 32 MB (later reused as h1)
  unsigned short* qkv   = (unsigned short*)(ws + 48300032);   // 24 MB (b,l,1536)
  unsigned short* vT    = (unsigned short*)(ws + 73465856);   //  8 MB
  unsigned short* yb    = (unsigned short*)(ws + 81854464);   //  8 MB
  float* res = (float*)(ws + 90243072);                       // 16 MB (resid1)
  // FFN2 split-K partials: 32 MB spanning [res, res+32MB) — res dead after LN1.
  float* p01 = res;
  unsigned short* h1  = cdm;    // reuse (cdist dead after attention)
  unsigned short* Xbf = qkv;    // reuse (qkv dead after attention); LN1 out bf16

  prep_all<<<3072 + Bb * Ll, 256, 0, stream>>>(x, wq, wk, wv, wo, w1, w2,
                                               xbf, sq, rmax, wqkvT, woT, w1T, w2T);

  // FUSED: triangular cdist (blocks 0..543) + QKV projection (544..1311)
  gemm_cq<<<1312, 256, 0, stream>>>(xbf, wqkvT, bq, bk, bv,
                                    cdm, qkv, sq, rmax, nmask);

  v_transpose<<<dim3(Ll / 64, Hh, Bb), 256, 0, stream>>>(qkv, vT);

  flash_attn<<<dim3(Ll / 64, Hh, Bb), 256, 0, stream>>>(qkv, vT, cdm, rmax, yb);

  // out projection + residual -> resid1 (f32)
  gemm_bt<2><<<dim3(4, 64, 1), 256, 0, stream>>>(yb, woT, Bb * Ll, Dd, Dd,
      bo, x, res, nullptr);

  // LN1 -> bf16 only (residual for LN2 is read back as bf16)
  ln_kernel<<<Bb * Ll, 256, 0, stream>>>(res, ln1g, ln1b, Xbf);

  // FFN
  gemm_bt<3><<<dim3(16, 64, 1), 256, 0, stream>>>(Xbf, w1T, Bb * Ll, 4 * Dd, Dd,
      b1, nullptr, nullptr, h1);
  // FFN2 split-K x2 -> raw f32 partials in p01 (p0 at 0, p1 at +M*N)
  gemm_bt<6><<<dim3(4, 64, 2), 256, 0, stream>>>(h1, w2T, Bb * Ll, Dd, 4 * Dd,
      nullptr, nullptr, p01, nullptr);

  ln2p_kernel<<<Bb * Ll, 256, 0, stream>>>(p01, b2, Xbf, ln2g, ln2b, outp);
}

// Round 15
// 222.783 us; speedup vs baseline: 1.1017x; 1.0207x over previous
//
#include <hip/hip_runtime.h>
#include <stdint.h>

#define GAS __attribute__((address_space(1)))
#define LAS __attribute__((address_space(3)))

typedef __attribute__((ext_vector_type(8))) __bf16 bf16x8;
typedef __attribute__((ext_vector_type(4))) float f32x4;

static constexpr int Bb = 4, Ll = 2048, Dd = 512, Hh = 8, DHd = 64;
static constexpr float LOG2E = 1.4426950408889634f;

__device__ __forceinline__ unsigned short f2bf(float f){
  unsigned u = __float_as_uint(f);
  u += 0x7fffu + ((u >> 16) & 1u);           // round-to-nearest-even
  return (unsigned short)(u >> 16);
}
__device__ __forceinline__ void gload16(const void* g, void* l){
  __builtin_amdgcn_global_load_lds((const GAS void*)g, (LAS void*)l, 16, 0, 0);
}
__device__ __forceinline__ f32x4 mfma16(bf16x8 a, bf16x8 b, f32x4 c){
  return __builtin_amdgcn_mfma_f32_16x16x32_bf16(a, b, c, 0, 0, 0);
}
__device__ __forceinline__ float exp2_hw(float x){   // v_exp_f32 = 2^x
  float r; asm("v_exp_f32 %0, %1" : "=v"(r) : "v"(x)); return r;
}

// ---------------------------------------------------------------------------
// fused prep: blocks [0,3072) = weight transposes (f32 (R,C) -> bf16 (C,R));
// blocks [3072, 3072+8192) = per-row sum-of-squares + x f32->bf16 cast + rmax=0.
__global__ __launch_bounds__(256) void prep_all(
    const float* __restrict__ x,
    const float* __restrict__ wq, const float* __restrict__ wk,
    const float* __restrict__ wv, const float* __restrict__ wo,
    const float* __restrict__ w1, const float* __restrict__ w2,
    unsigned short* __restrict__ xbf, float* __restrict__ sq,
    float* __restrict__ rmax,
    unsigned short* __restrict__ wqkvT, unsigned short* __restrict__ woT,
    unsigned short* __restrict__ w1T, unsigned short* __restrict__ w2T)
{
  __shared__ float t[32][33];
  __shared__ float red[4];
  int bid = blockIdx.x;
  if (bid >= 3072){
    // ---- sumsq + cast + rmax zero ----
    int row = bid - 3072, tid = threadIdx.x;
    float2 v = ((const float2*)(x + (size_t)row * Dd))[tid];
    ((unsigned*)(xbf + (size_t)row * Dd))[tid] =
        (unsigned)f2bf(v.x) | ((unsigned)f2bf(v.y) << 16);
    float s2 = v.x * v.x + v.y * v.y;
    #pragma unroll
    for (int s = 1; s < 64; s <<= 1) s2 += __shfl_xor(s2, s, 64);
    if ((tid & 63) == 0) red[tid >> 6] = s2;
    __syncthreads();
    if (tid == 0){
      sq[row] = red[0] + red[1] + red[2] + red[3];
      rmax[row] = 0.f;
    }
    return;
  }
  // ---- weight transpose ----
  const float* in; unsigned short* out; int R, C, bx, by;
  if (bid < 1024){
    int s = bid >> 8, tt = bid & 255;
    in  = s == 0 ? wq : s == 1 ? wk : s == 2 ? wv : wo;
    out = s == 3 ? woT : wqkvT + s * 512 * 512;
    R = 512; C = 512; bx = tt & 15; by = tt >> 4;
  } else if (bid < 2048){
    int tt = bid - 1024; in = w1; out = w1T; R = 512; C = 2048; bx = tt & 63; by = tt >> 6;
  } else {
    int tt = bid - 2048; in = w2; out = w2T; R = 2048; C = 512; bx = tt & 15; by = tt >> 4;
  }
  int tx = threadIdx.x & 31, ty = threadIdx.x >> 5;
  int c0 = bx * 32, r0 = by * 32;
  #pragma unroll
  for (int j = 0; j < 32; j += 8) t[ty + j][tx] = in[(size_t)(r0 + ty + j) * C + c0 + tx];
  __syncthreads();
  #pragma unroll
  for (int j = 0; j < 32; j += 8) out[(size_t)(c0 + ty + j) * R + r0 + tx] = f2bf(t[tx][ty + j]);
}

// ---------------------------------------------------------------------------
// v slice of fused qkv (b,l,1536) -> vT (b,h,dh,l) bf16. grid (L/64,H,B), blk 256
__global__ __launch_bounds__(256) void v_transpose(const unsigned short* __restrict__ qkv,
                                                   unsigned short* __restrict__ vT){
  int b = blockIdx.z, h = blockIdx.y, l0 = blockIdx.x * 64;
  int tid = threadIdx.x;
  __shared__ unsigned short t[64 * 64];
  #pragma unroll
  for (int it = 0; it < 2; ++it){
    int row = tid >> 2;                 // local l
    int c = (tid & 3) + it * 4;         // 16B granule (8 dh)
    uint4 d = *(const uint4*)(qkv + (size_t)(b * Ll + l0 + row) * 1536 + 1024 + h * DHd + c * 8);
    *(uint4*)((char*)t + row * 128 + ((c ^ (row & 7)) << 4)) = d;
  }
  __syncthreads();
  #pragma unroll
  for (int it = 0; it < 2; ++it){
    int dh = tid >> 2;
    int c2 = (tid & 3) + it * 4;        // granule along l (8 l-values)
    unsigned pk[4];
    #pragma unroll
    for (int p = 0; p < 4; ++p){
      unsigned short e0, e1;
      {
        int ll = c2 * 8 + p * 2;
        e0 = *(const unsigned short*)((const char*)t + ll * 128 +
              ((((dh >> 3) ^ (ll & 7))) << 4) + ((dh & 7) << 1));
        ll = c2 * 8 + p * 2 + 1;
        e1 = *(const unsigned short*)((const char*)t + ll * 128 +
              ((((dh >> 3) ^ (ll & 7))) << 4) + ((dh & 7) << 1));
      }
      pk[p] = (unsigned)e0 | ((unsigned)e1 << 16);
    }
    uint4 o; o.x = pk[0]; o.y = pk[1]; o.z = pk[2]; o.w = pk[3];
    *(uint4*)(vT + ((size_t)(b * Hh + h) * DHd + dh) * Ll + l0 + c2 * 8) = o;
  }
}

// ---------------------------------------------------------------------------
// FUSED cdist + QKV GEMM (both K=512, independent, share the MFMA main loop).
// 128x128 tile, BK=64, 2-phase LDS dbuf (R12/R14-proven operating point).
// blocks [0,544): triangular cdist (136 upper-tri tiles x 4 batches);
// blocks [544,1312): fused QKV projection (12 x 64 tiles), 3-way bias.
__global__ __launch_bounds__(256) void gemm_cq(
    const unsigned short* __restrict__ xbf,
    const unsigned short* __restrict__ wqkvT,
    const float* __restrict__ bq, const float* __restrict__ bk,
    const float* __restrict__ bv,
    unsigned short* __restrict__ cdm, unsigned short* __restrict__ qkv,
    const float* __restrict__ sq, float* __restrict__ rmax,
    const float* __restrict__ mask)
{
  const int bid = blockIdx.x;
  const bool isc = bid < 544;
  const unsigned short *Ap, *Bp;
  int m0, n0, bxx = 0, byy = 0, zb = 0;
  if (isc){
    zb = bid / 136;
    int tt = bid - zb * 136, byv = 0;
    while (tt >= 16 - byv){ tt -= 16 - byv; byv++; }
    byy = byv; bxx = byv + tt;
    m0 = byy * 128; n0 = bxx * 128;
    Ap = xbf + (size_t)zb * Ll * Dd; Bp = Ap;
  } else {
    int t = bid - 544;
    int bx = t % 12, by = t / 12;
    m0 = by * 128; n0 = bx * 128;
    Ap = xbf; Bp = wqkvT;
  }
  const int tid = threadIdx.x, w = tid >> 6, l = tid & 63;
  const int wm = w >> 1, wn = w & 1;
  __shared__ unsigned short lA[2][128 * 64];
  __shared__ unsigned short lB[2][128 * 64];
  f32x4 acc[4][4];
  const f32x4 z4 = {0.f, 0.f, 0.f, 0.f};
  #pragma unroll
  for (int i = 0; i < 4; i++){
    #pragma unroll
    for (int j = 0; j < 4; j++) acc[i][j] = z4;
  }
  const int srow = w * 8 + (l >> 3);
  const int sc = l & 7;

  // prologue: stage k-tile 0 (K = 512 for both modes)
  #pragma unroll
  for (int j = 0; j < 4; j++){
    int row = j * 32 + srow;
    gload16(Ap + (size_t)(m0 + row) * Dd + ((sc ^ (row & 7)) << 3),
            &lA[0][0] + j * 2048 + w * 512);
    gload16(Bp + (size_t)(n0 + row) * Dd + ((sc ^ (row & 7)) << 3),
            &lB[0][0] + j * 2048 + w * 512);
  }
  __syncthreads();

  int cur = 0;
  for (int k0 = 0; k0 < Dd; k0 += 64, cur ^= 1){
    if (k0 + 64 < Dd){
      #pragma unroll
      for (int j = 0; j < 4; j++){
        int row = j * 32 + srow;
        gload16(Ap + (size_t)(m0 + row) * Dd + k0 + 64 + ((sc ^ (row & 7)) << 3),
                &lA[cur ^ 1][0] + j * 2048 + w * 512);
        gload16(Bp + (size_t)(n0 + row) * Dd + k0 + 64 + ((sc ^ (row & 7)) << 3),
                &lB[cur ^ 1][0] + j * 2048 + w * 512);
      }
    }
    bf16x8 af[4][2], bvv[4][2];
    #pragma unroll
    for (int kk = 0; kk < 2; kk++){
      #pragma unroll
      for (int f = 0; f < 4; f++){
        int ra = wm * 64 + f * 16 + (l & 15);
        af[f][kk] = *(const bf16x8*)((const char*)&lA[cur][0] + ra * 128 +
                      (((kk * 4 + (l >> 4)) ^ (ra & 7)) << 4));
        int rb = wn * 64 + f * 16 + (l & 15);
        bvv[f][kk] = *(const bf16x8*)((const char*)&lB[cur][0] + rb * 128 +
                      (((kk * 4 + (l >> 4)) ^ (rb & 7)) << 4));
      }
    }
    #pragma unroll
    for (int mf = 0; mf < 4; mf++){
      #pragma unroll
      for (int nf = 0; nf < 4; nf++){
        #pragma unroll
        for (int kk = 0; kk < 2; kk++)
          acc[mf][nf] = mfma16(af[mf][kk], bvv[nf][kk], acc[mf][nf]);
      }
    }
    __syncthreads();
  }

  if (isc){
    unsigned short* outb = cdm + (size_t)zb * Ll * Ll;
    const float* sqz = sq + zb * Ll;
    const float* mkz = mask + zb * Ll;
    float* rmz = rmax + zb * Ll;
    float sqc[4], mkc[4];
    #pragma unroll
    for (int nf = 0; nf < 4; nf++){
      int col = n0 + wn * 64 + nf * 16 + (l & 15);
      sqc[nf] = sqz[col]; mkc[nf] = mkz[col];
    }
    #pragma unroll
    for (int mf = 0; mf < 4; mf++){
      #pragma unroll
      for (int r = 0; r < 4; r++){
        int row = m0 + wm * 64 + mf * 16 + (l >> 4) * 4 + r;
        float sqi = sqz[row], mi = mkz[row];
        #pragma unroll
        for (int nf = 0; nf < 4; nf++){
          float d2 = sqi + sqc[nf] - 2.f * acc[mf][nf][r];
          acc[mf][nf][r] = sqrtf(fmaxf(d2, 0.f)) * (mi * mkc[nf]) * LOG2E + 8.f;
        }
      }
    }
    #pragma unroll
    for (int mf = 0; mf < 4; mf++){
      #pragma unroll
      for (int r = 0; r < 4; r++){
        int row = m0 + wm * 64 + mf * 16 + (l >> 4) * 4 + r;
        float rm = 0.f;
        #pragma unroll
        for (int nf = 0; nf < 4; nf++){
          int col = n0 + wn * 64 + nf * 16 + (l & 15);
          outb[(size_t)row * Ll + col] = f2bf(acc[mf][nf][r]);
          rm = fmaxf(rm, acc[mf][nf][r]);
        }
        #pragma unroll
        for (int t = 1; t < 16; t <<= 1) rm = fmaxf(rm, __shfl_xor(rm, t, 64));
        if ((l & 15) == 0) atomicMax((int*)(rmz + row), __float_as_int(rm));
      }
    }
    if (bxx != byy){
      #pragma unroll
      for (int nf = 0; nf < 4; nf++){
        int col = n0 + wn * 64 + nf * 16 + (l & 15);
        float cm = 0.f;
        #pragma unroll
        for (int mf = 0; mf < 4; mf++){
          uint2 pk2;
          pk2.x = (unsigned)f2bf(acc[mf][nf][0]) | ((unsigned)f2bf(acc[mf][nf][1]) << 16);
          pk2.y = (unsigned)f2bf(acc[mf][nf][2]) | ((unsigned)f2bf(acc[mf][nf][3]) << 16);
          int rowb = m0 + wm * 64 + mf * 16 + (l >> 4) * 4;
          *(uint2*)(outb + (size_t)col * Ll + rowb) = pk2;
          cm = fmaxf(cm, fmaxf(fmaxf(acc[mf][nf][0], acc[mf][nf][1]),
                               fmaxf(acc[mf][nf][2], acc[mf][nf][3])));
        }
        cm = fmaxf(cm, __shfl_xor(cm, 16, 64));
        cm = fmaxf(cm, __shfl_xor(cm, 32, 64));
        if ((l >> 4) == 0) atomicMax((int*)(rmz + col), __float_as_int(cm));
      }
    }
  } else {
    #pragma unroll
    for (int mf = 0; mf < 4; mf++){
      #pragma unroll
      for (int r = 0; r < 4; r++){
        int row = m0 + wm * 64 + mf * 16 + (l >> 4) * 4 + r;
        #pragma unroll
        for (int nf = 0; nf < 4; nf++){
          int col = n0 + wn * 64 + nf * 16 + (l & 15);
          const float* bp = col < 512 ? bq : (col < 1024 ? bk : bv);
          float v = acc[mf][nf][r] + bp[col & 511];
          qkv[(size_t)row * 1536 + col] = f2bf(v);
        }
      }
    }
  }
}

// ---------------------------------------------------------------------------
// 128x128x64 bf16 MFMA GEMM, B transposed (N,K) row-major, 2-phase LDS dbuf.
// MODE 3: relu(+bias) -> bf16
// MODE 6: SPLIT-K x2 (z = k-half): bf16 partials -> outb + z*M*N
// MODE 7: +bias +extra(f32) -> bf16 (attn out-proj + residual)
template<int MODE>
__global__ __launch_bounds__(256) void gemm_bt(
    const unsigned short* __restrict__ A,
    const unsigned short* __restrict__ Bt,
    int M, int N, int K,
    const float* __restrict__ bias,
    const float* __restrict__ extra,
    unsigned short* __restrict__ outb)
{
  int m0 = blockIdx.y * 128, n0 = blockIdx.x * 128;
  if (MODE == 6){                      // split-K: offset into the k-half
    int z = blockIdx.z;
    A    += (size_t)z * (K >> 1);
    Bt   += (size_t)z * (K >> 1);
    outb += (size_t)z * (size_t)M * N;
  }
  const int KL = (MODE == 6) ? (K >> 1) : K;
  const int tid = threadIdx.x, w = tid >> 6, l = tid & 63;
  const int wm = w >> 1, wn = w & 1;
  __shared__ unsigned short lA[2][128 * 64];
  __shared__ unsigned short lB[2][128 * 64];
  f32x4 acc[4][4];
  const f32x4 z4 = {0.f, 0.f, 0.f, 0.f};
  #pragma unroll
  for (int i = 0; i < 4; i++){
    #pragma unroll
    for (int j = 0; j < 4; j++) acc[i][j] = z4;
  }
  const int srow = w * 8 + (l >> 3);
  const int sc = l & 7;

  #pragma unroll
  for (int j = 0; j < 4; j++){
    int row = j * 32 + srow;
    gload16(A + (size_t)(m0 + row) * K + ((sc ^ (row & 7)) << 3),
            &lA[0][0] + j * 2048 + w * 512);
    gload16(Bt + (size_t)(n0 + row) * K + ((sc ^ (row & 7)) << 3),
            &lB[0][0] + j * 2048 + w * 512);
  }
  __syncthreads();

  int cur = 0;
  for (int k0 = 0; k0 < KL; k0 += 64, cur ^= 1){
    if (k0 + 64 < KL){
      #pragma unroll
      for (int j = 0; j < 4; j++){
        int row = j * 32 + srow;
        gload16(A + (size_t)(m0 + row) * K + k0 + 64 + ((sc ^ (row & 7)) << 3),
                &lA[cur ^ 1][0] + j * 2048 + w * 512);
        gload16(Bt + (size_t)(n0 + row) * K + k0 + 64 + ((sc ^ (row & 7)) << 3),
                &lB[cur ^ 1][0] + j * 2048 + w * 512);
      }
    }
    bf16x8 af[4][2], bv[4][2];
    #pragma unroll
    for (int kk = 0; kk < 2; kk++){
      #pragma unroll
      for (int f = 0; f < 4; f++){
        int ra = wm * 64 + f * 16 + (l & 15);
        af[f][kk] = *(const bf16x8*)((const char*)&lA[cur][0] + ra * 128 +
                      (((kk * 4 + (l >> 4)) ^ (ra & 7)) << 4));
        int rb = wn * 64 + f * 16 + (l & 15);
        bv[f][kk] = *(const bf16x8*)((const char*)&lB[cur][0] + rb * 128 +
                      (((kk * 4 + (l >> 4)) ^ (rb & 7)) << 4));
      }
    }
    #pragma unroll
    for (int mf = 0; mf < 4; mf++){
      #pragma unroll
      for (int nf = 0; nf < 4; nf++){
        #pragma unroll
        for (int kk = 0; kk < 2; kk++)
          acc[mf][nf] = mfma16(af[mf][kk], bv[nf][kk], acc[mf][nf]);
      }
    }
    __syncthreads();
  }

  #pragma unroll
  for (int mf = 0; mf < 4; mf++){
    #pragma unroll
    for (int r = 0; r < 4; r++){
      int row = m0 + wm * 64 + mf * 16 + (l >> 4) * 4 + r;
      #pragma unroll
      for (int nf = 0; nf < 4; nf++){
        int col = n0 + wn * 64 + nf * 16 + (l & 15);
        if (MODE == 6){
          outb[(size_t)row * N + col] = f2bf(acc[mf][nf][r]);
        } else if (MODE == 3){
          float v = acc[mf][nf][r] + bias[col];
          outb[(size_t)row * N + col] = f2bf(fmaxf(v, 0.f));
        } else {  // MODE 7
          float v = acc[mf][nf][r] + bias[col] + extra[(size_t)row * N + col];
          outb[(size_t)row * N + col] = f2bf(v);
        }
      }
    }
  }
}

// ---------------------------------------------------------------------------
// flash attention, SWAPPED QK^T, FIXED-m exp2 softmax, QBLK=64 (R12-proven).
// grid (L/64, H, B) = 1024 blocks, block 256 (4 waves x 16 q-rows).
// LDS 40KB -> 4 blocks/CU.
__global__ __launch_bounds__(256, 4) void flash_attn(
    const unsigned short* __restrict__ qkv,
    const unsigned short* __restrict__ vT,
    const unsigned short* __restrict__ cdm,   // cd*LOG2E + 8
    const float* __restrict__ rmax,           // max_k of stored cdm
    unsigned short* __restrict__ y)
{
  const int b = blockIdx.z, h = blockIdx.y, q0 = blockIdx.x * 64;
  const int tid = threadIdx.x, w = tid >> 6, l = tid & 63;
  const int ql = l & 15, lg = l >> 4;
  __shared__ unsigned short QPs[64 * 64];    //  8KB: Q staging; reused as P
  __shared__ unsigned short Ks[2][64 * 64];  // 16KB dbuf
  __shared__ unsigned short Vs[2][64 * 64];  // 16KB dbuf

  const int srow = w * 8 + (l >> 3);
  const int sc = l & 7;
  const unsigned short* kbase = qkv + (size_t)b * Ll * 1536 + 512 + h * DHd;
  const unsigned short* vbase = vT + (size_t)(b * Hh + h) * DHd * Ll;

  // prologue: stage Q + tile 0 of K/V
  #pragma unroll
  for (int j = 0; j < 2; j++){
    int row = j * 32 + srow;
    gload16(qkv + (size_t)(b * Ll + q0 + row) * 1536 + h * DHd + ((sc ^ (row & 7)) << 3),
            QPs + j * 2048 + w * 512);
    gload16(kbase + (size_t)row * 1536 + ((sc ^ (row & 7)) << 3),
            &Ks[0][0] + j * 2048 + w * 512);
    gload16(vbase + (size_t)row * Ll + ((sc ^ (row & 7)) << 3),
            &Vs[0][0] + j * 2048 + w * 512);
  }

  const int qg = q0 + w * 16 + ql;                 // this lane's q-row
  const float rmx8 = rmax[b * Ll + qg] - 8.f;      // diag correction
  const unsigned short* cdrow = cdm + (size_t)(b * Ll + qg) * Ll;

  // register-prefetch cd bias for tile 0
  uint2 cdn[4];
  #pragma unroll
  for (int nf = 0; nf < 4; nf++)
    cdn[nf] = *(const uint2*)(cdrow + nf * 16 + lg * 4);

  f32x4 o[4];
  const f32x4 z4 = {0.f, 0.f, 0.f, 0.f};
  #pragma unroll
  for (int nf = 0; nf < 4; nf++) o[nf] = z4;
  float lsum = 0.f;

  __syncthreads();   // Q + tile 0 resident

  // hoist Q B-fragments (constant over k-loop); QPs region free afterwards
  bf16x8 qa[2];
  #pragma unroll
  for (int kk = 0; kk < 2; kk++){
    int ra = w * 16 + ql;
    qa[kk] = *(const bf16x8*)((const char*)QPs + ra * 128 +
               (((kk * 4 + lg) ^ (ql & 7)) << 4));
  }

  const int NT = Ll / 64;
  for (int t = 0; t < NT; ++t){
    const int k0 = t * 64;
    const int cur = t & 1;

    uint2 cdc[4];                       // this tile's bias (prefetched last tile)
    #pragma unroll
    for (int nf = 0; nf < 4; nf++) cdc[nf] = cdn[nf];

    if (t + 1 < NT){
      const int kn = k0 + 64;
      #pragma unroll
      for (int nf = 0; nf < 4; nf++)    // prefetch next tile's bias
        cdn[nf] = *(const uint2*)(cdrow + kn + nf * 16 + lg * 4);
      #pragma unroll
      for (int j = 0; j < 2; j++){      // stage next K/V (overlaps compute)
        int row = j * 32 + srow;
        gload16(kbase + (size_t)(kn + row) * 1536 + ((sc ^ (row & 7)) << 3),
                &Ks[cur ^ 1][0] + j * 2048 + w * 512);
        gload16(vbase + (size_t)row * Ll + kn + ((sc ^ (row & 7)) << 3),
                &Vs[cur ^ 1][0] + j * 2048 + w * 512);
      }
    }

    // S^T = K Q^T : lane gets q = w*16+ql, k = nf*16 + lg*4 + r
    f32x4 s[4];
    #pragma unroll
    for (int nf = 0; nf < 4; nf++){
      s[nf] = z4;
      #pragma unroll
      for (int kk = 0; kk < 2; kk++){
        int rb = nf * 16 + ql;
        bf16x8 kb = *(const bf16x8*)((const char*)Ks[cur] + rb * 128 +
                      (((kk * 4 + lg) ^ (ql & 7)) << 4));
        s[nf] = mfma16(kb, qa[kk], s[nf]);
      }
    }

    // ---- fixed-m softmax: p = 2^(qk*c - cdm'), no running max ----
    float sv[16];
    #pragma unroll
    for (int nf = 0; nf < 4; nf++){
      float c0 = __uint_as_float(cdc[nf].x << 16);
      float c1 = __uint_as_float(cdc[nf].x & 0xffff0000u);
      float c2 = __uint_as_float(cdc[nf].y << 16);
      float c3 = __uint_as_float(cdc[nf].y & 0xffff0000u);
      sv[nf * 4 + 0] = fmaf(s[nf][0], 0.125f * LOG2E, -c0);
      sv[nf * 4 + 1] = fmaf(s[nf][1], 0.125f * LOG2E, -c1);
      sv[nf * 4 + 2] = fmaf(s[nf][2], 0.125f * LOG2E, -c2);
      sv[nf * 4 + 3] = fmaf(s[nf][3], 0.125f * LOG2E, -c3);
    }
    if (k0 == q0){            // diagonal tile: subtract (rmax_stored - 8)
      #pragma unroll
      for (int nf = 0; nf < 4; nf++) if (nf == w){
        #pragma unroll
        for (int r = 0; r < 4; r++)
          if (lg * 4 + r == ql) sv[nf * 4 + r] -= rmx8;
      }
    }

    float p[16], ps = 0.f;
    #pragma unroll
    for (int i = 0; i < 16; i++){ p[i] = exp2_hw(sv[i]); ps += p[i]; }
    lsum += ps;                         // per-lane partial; reduce at end

    // P -> LDS (wave-private region of QPs), packed b64 per nf
    #pragma unroll
    for (int nf = 0; nf < 4; nf++){
      unsigned d0, d1;
      asm("v_cvt_pk_bf16_f32 %0, %1, %2" : "=v"(d0) : "v"(p[nf*4+0]), "v"(p[nf*4+1]));
      asm("v_cvt_pk_bf16_f32 %0, %1, %2" : "=v"(d1) : "v"(p[nf*4+2]), "v"(p[nf*4+3]));
      uint2 pk2; pk2.x = d0; pk2.y = d1;
      *(uint2*)((char*)QPs + w * 2048 + ql * 128 +
                ((nf * 32 + lg * 8) ^ ((ql & 7) << 4))) = pk2;
    }

    // PV: A = P (rows = q), B = V (cols = dh)
    bf16x8 pa[2];
    #pragma unroll
    for (int kk = 0; kk < 2; kk++)
      pa[kk] = *(const bf16x8*)((const char*)QPs + w * 2048 + ql * 128 +
                 ((((kk * 4 + lg)) ^ (ql & 7)) << 4));
    #pragma unroll
    for (int nf = 0; nf < 4; nf++){
      #pragma unroll
      for (int kk = 0; kk < 2; kk++){
        int rv = nf * 16 + ql;
        bf16x8 vb = *(const bf16x8*)((const char*)Vs[cur] + rv * 128 +
                      (((kk * 4 + lg) ^ (ql & 7)) << 4));
        o[nf] = mfma16(pa[kk], vb, o[nf]);
      }
    }
    __syncthreads();   // staged loads drained; buffers safe to swap
  }

  // epilogue: O rows are q = q0 + w*16 + lg*4 + r; reduce lsum across lg now
  float ltot = lsum;
  ltot += __shfl_xor(ltot, 16, 64);
  ltot += __shfl_xor(ltot, 32, 64);
  float lf[4];
  #pragma unroll
  for (int r = 0; r < 4; r++)
    lf[r] = __shfl(ltot, (l & 48) | (lg * 4 + r), 64);
  #pragma unroll
  for (int nf = 0; nf < 4; nf++){
    #pragma unroll
    for (int r = 0; r < 4; r++){
      int qo = q0 + w * 16 + lg * 4 + r;
      float v = o[nf][r] / lf[r];
      y[(size_t)(b * Ll + qo) * Dd + h * DHd + nf * 16 + ql] = f2bf(v);
    }
  }
}

// ---------------------------------------------------------------------------
// layernorm over D=512, bf16 input -> bf16 out.  grid = B*L, block 256.
__global__ __launch_bounds__(256) void ln_kernel(const unsigned short* __restrict__ in,
                                                 const float* __restrict__ g,
                                                 const float* __restrict__ bt,
                                                 unsigned short* __restrict__ outb){
  int row = blockIdx.x, tid = threadIdx.x;
  unsigned u = ((const unsigned*)(in + (size_t)row * Dd))[tid];
  float vx = __uint_as_float(u << 16);
  float vy = __uint_as_float(u & 0xffff0000u);
  float s = vx + vy, s2 = vx * vx + vy * vy;
  #pragma unroll
  for (int t = 1; t < 64; t <<= 1){ s += __shfl_xor(s, t, 64); s2 += __shfl_xor(s2, t, 64); }
  __shared__ float red[8];
  if ((tid & 63) == 0){ red[tid >> 6] = s; red[4 + (tid >> 6)] = s2; }
  __syncthreads();
  float S  = red[0] + red[1] + red[2] + red[3];
  float S2 = red[4] + red[5] + red[6] + red[7];
  float mu = S * (1.f / 512.f);
  float var = fmaxf(S2 * (1.f / 512.f) - mu * mu, 0.f);
  float rs = rsqrtf(var + 1e-5f);
  int c = tid * 2;
  float o0 = (vx - mu) * rs * g[c] + bt[c];
  float o1 = (vy - mu) * rs * g[c + 1] + bt[c + 1];
  ((unsigned*)(outb + (size_t)row * Dd))[tid] =
      (unsigned)f2bf(o0) | ((unsigned)f2bf(o1) << 16);
}

// ---------------------------------------------------------------------------
// layernorm over (p0 + p1 + bias + extra_bf16): combines FFN2 bf16 split-K
// partials, adds the bf16 residual (LN1 out), then LN.  grid = B*L, block 256.
__global__ __launch_bounds__(256) void ln2p_kernel(
    const unsigned short* __restrict__ p01,     // [2][M][512] bf16 FFN2 partials
    const float* __restrict__ bias,
    const unsigned short* __restrict__ extra,   // residual, bf16 (LN1 out)
    const float* __restrict__ g, const float* __restrict__ bt,
    float* __restrict__ outf)
{
  int row = blockIdx.x, tid = threadIdx.x;
  unsigned u0 = ((const unsigned*)(p01 + (size_t)row * Dd))[tid];
  unsigned u1 = ((const unsigned*)(p01 + (size_t)Bb * Ll * Dd + (size_t)row * Dd))[tid];
  unsigned ex = ((const unsigned*)(extra + (size_t)row * Dd))[tid];
  float a0x = __uint_as_float(u0 << 16),        a0y = __uint_as_float(u0 & 0xffff0000u);
  float a1x = __uint_as_float(u1 << 16),        a1y = __uint_as_float(u1 & 0xffff0000u);
  float ex0 = __uint_as_float(ex << 16),        ex1 = __uint_as_float(ex & 0xffff0000u);
  int c = tid * 2;
  float vx = a0x + a1x + bias[c]     + ex0;
  float vy = a0y + a1y + bias[c + 1] + ex1;
  float s = vx + vy, s2 = vx * vx + vy * vy;
  #pragma unroll
  for (int t = 1; t < 64; t <<= 1){ s += __shfl_xor(s, t, 64); s2 += __shfl_xor(s2, t, 64); }
  __shared__ float red[8];
  if ((tid & 63) == 0){ red[tid >> 6] = s; red[4 + (tid >> 6)] = s2; }
  __syncthreads();
  float S  = red[0] + red[1] + red[2] + red[3];
  float S2 = red[4] + red[5] + red[6] + red[7];
  float mu = S * (1.f / 512.f);
  float var = fmaxf(S2 * (1.f / 512.f) - mu * mu, 0.f);
  float rs = rsqrtf(var + 1e-5f);
  float o0 = (vx - mu) * rs * g[c] + bt[c];
  float o1 = (vy - mu) * rs * g[c + 1] + bt[c + 1];
  float2 ov; ov.x = o0; ov.y = o1;
  ((float2*)(outf + (size_t)row * Dd))[tid] = ov;
}

// ---------------------------------------------------------------------------
extern "C" void kernel_launch(void* const* d_in, const int* in_sizes, int n_in,
                              void* d_out, int out_size, void* d_ws, size_t ws_size,
                              hipStream_t stream){
  const float* x     = (const float*)d_in[0];
  const float* nmask = (const float*)d_in[1];
  const float* wq = (const float*)d_in[2];  const float* bq = (const float*)d_in[3];
  const float* wk = (const float*)d_in[4];  const float* bk = (const float*)d_in[5];
  const float* wv = (const float*)d_in[6];  const float* bv = (const float*)d_in[7];
  const float* wo = (const float*)d_in[8];  const float* bo = (const float*)d_in[9];
  const float* ln1g = (const float*)d_in[10]; const float* ln1b = (const float*)d_in[11];
  const float* w1 = (const float*)d_in[12]; const float* b1 = (const float*)d_in[13];
  const float* w2 = (const float*)d_in[14]; const float* b2 = (const float*)d_in[15];
  const float* ln2g = (const float*)d_in[16]; const float* ln2b = (const float*)d_in[17];
  float* outp = (float*)d_out;
  char* ws = (char*)d_ws;

  // workspace layout (bytes)
  unsigned short* xbf   = (unsigned short*)(ws + 0);          //  8 MB
  float* sq   = (float*)(ws + 8388608);                       //  32 KB
  float* rmax = (float*)(ws + 8421376);                       //  32 KB
  unsigned short* wqkvT = (unsigned short*)(ws + 8454144);    //  1.5 MB (1536 x 512)
  unsigned short* woT   = (unsigned short*)(ws + 10027008);   //  512 KB
  unsigned short* w1T   = (unsigned short*)(ws + 10551296);   //  2 MB
  unsigned short* w2T   = (unsigned short*)(ws + 12648448);   //  2 MB
  unsigned short* cdm   = (unsigned short*)(ws + 14745600);   // 32 MB (later reused as h1)
  unsigned short* qkv   = (unsigned short*)(ws + 48300032);   // 24 MB (b,l,1536)
  unsigned short* vT    = (unsigned short*)(ws + 73465856);   //  8 MB
  unsigned short* yb    = (unsigned short*)(ws + 81854464);   //  8 MB
  unsigned short* resb  = (unsigned short*)(ws + 90243072);   //  8 MB (attn residual, bf16)
  // FFN2 bf16 split-K partials: 16 MB at ws+98631680 (resb dead after LN1)
  unsigned short* p01   = (unsigned short*)(ws + 98631680);
  unsigned short* h1  = cdm;    // reuse (cdist dead after attention)
  unsigned short* Xbf = qkv;    // reuse (qkv dead after attention); LN1 out bf16

  prep_all<<<3072 + Bb * Ll, 256, 0, stream>>>(x, wq, wk, wv, wo, w1, w2,
                                               xbf, sq, rmax, wqkvT, woT, w1T, w2T);

  // FUSED: triangular cdist (blocks 0..543) + QKV projection (544..1311)
  gemm_cq<<<1312, 256, 0, stream>>>(xbf, wqkvT, bq, bk, bv,
                                    cdm, qkv, sq, rmax, nmask);

  v_transpose<<<dim3(Ll / 64, Hh, Bb), 256, 0, stream>>>(qkv, vT);

  flash_attn<<<dim3(Ll / 64, Hh, Bb), 256, 0, stream>>>(qkv, vT, cdm, rmax, yb);

  // out projection + residual -> resb (bf16)
  gemm_bt<7><<<dim3(4, 64, 1), 256, 0, stream>>>(yb, woT, Bb * Ll, Dd, Dd,
      bo, x, resb);

  // LN1 (bf16 in) -> bf16 out (residual for LN2)
  ln_kernel<<<Bb * Ll, 256, 0, stream>>>(resb, ln1g, ln1b, Xbf);

  // FFN
  gemm_bt<3><<<dim3(16, 64, 1), 256, 0, stream>>>(Xbf, w1T, Bb * Ll, 4 * Dd, Dd,
      b1, nullptr, h1);
  // FFN2 split-K x2 -> bf16 partials in p01 (p0 at 0, p1 at +M*N)
  gemm_bt<6><<<dim3(4, 64, 2), 256, 0, stream>>>(h1, w2T, Bb * Ll, Dd, 4 * Dd,
      nullptr, nullptr, p01);

  ln2p_kernel<<<Bb * Ll, 256, 0, stream>>>(p01, b2, Xbf, ln2g, ln2b, outp);
}

// Round 16
// 219.791 us; speedup vs baseline: 1.1167x; 1.0136x over previous
//
#include <hip/hip_runtime.h>
#include <stdint.h>

#define GAS __attribute__((address_space(1)))
#define LAS __attribute__((address_space(3)))

typedef __attribute__((ext_vector_type(8))) __bf16 bf16x8;
typedef __attribute__((ext_vector_type(4))) float f32x4;

static constexpr int Bb = 4, Ll = 2048, Dd = 512, Hh = 8, DHd = 64;
static constexpr float LOG2E = 1.4426950408889634f;

__device__ __forceinline__ unsigned short f2bf(float f){
  unsigned u = __float_as_uint(f);
  u += 0x7fffu + ((u >> 16) & 1u);           // round-to-nearest-even
  return (unsigned short)(u >> 16);
}
__device__ __forceinline__ void gload16(const void* g, void* l){
  __builtin_amdgcn_global_load_lds((const GAS void*)g, (LAS void*)l, 16, 0, 0);
}
__device__ __forceinline__ f32x4 mfma16(bf16x8 a, bf16x8 b, f32x4 c){
  return __builtin_amdgcn_mfma_f32_16x16x32_bf16(a, b, c, 0, 0, 0);
}
__device__ __forceinline__ float exp2_hw(float x){   // v_exp_f32 = 2^x
  float r; asm("v_exp_f32 %0, %1" : "=v"(r) : "v"(x)); return r;
}

// ---------------------------------------------------------------------------
// fused prep: blocks [0,3072) = weight transposes (f32 (R,C) -> bf16 (C,R));
// blocks [3072, 3072+8192) = per-row sum-of-squares + x f32->bf16 cast + rmax=0.
__global__ __launch_bounds__(256) void prep_all(
    const float* __restrict__ x,
    const float* __restrict__ wq, const float* __restrict__ wk,
    const float* __restrict__ wv, const float* __restrict__ wo,
    const float* __restrict__ w1, const float* __restrict__ w2,
    unsigned short* __restrict__ xbf, float* __restrict__ sq,
    float* __restrict__ rmax,
    unsigned short* __restrict__ wqkvT, unsigned short* __restrict__ woT,
    unsigned short* __restrict__ w1T, unsigned short* __restrict__ w2T)
{
  __shared__ float t[32][33];
  __shared__ float red[4];
  int bid = blockIdx.x;
  if (bid >= 3072){
    // ---- sumsq + cast + rmax zero ----
    int row = bid - 3072, tid = threadIdx.x;
    float2 v = ((const float2*)(x + (size_t)row * Dd))[tid];
    ((unsigned*)(xbf + (size_t)row * Dd))[tid] =
        (unsigned)f2bf(v.x) | ((unsigned)f2bf(v.y) << 16);
    float s2 = v.x * v.x + v.y * v.y;
    #pragma unroll
    for (int s = 1; s < 64; s <<= 1) s2 += __shfl_xor(s2, s, 64);
    if ((tid & 63) == 0) red[tid >> 6] = s2;
    __syncthreads();
    if (tid == 0){
      sq[row] = red[0] + red[1] + red[2] + red[3];
      rmax[row] = 0.f;
    }
    return;
  }
  // ---- weight transpose ----
  const float* in; unsigned short* out; int R, C, bx, by;
  if (bid < 1024){
    int s = bid >> 8, tt = bid & 255;
    in  = s == 0 ? wq : s == 1 ? wk : s == 2 ? wv : wo;
    out = s == 3 ? woT : wqkvT + s * 512 * 512;
    R = 512; C = 512; bx = tt & 15; by = tt >> 4;
  } else if (bid < 2048){
    int tt = bid - 1024; in = w1; out = w1T; R = 512; C = 2048; bx = tt & 63; by = tt >> 6;
  } else {
    int tt = bid - 2048; in = w2; out = w2T; R = 2048; C = 512; bx = tt & 15; by = tt >> 4;
  }
  int tx = threadIdx.x & 31, ty = threadIdx.x >> 5;
  int c0 = bx * 32, r0 = by * 32;
  #pragma unroll
  for (int j = 0; j < 32; j += 8) t[ty + j][tx] = in[(size_t)(r0 + ty + j) * C + c0 + tx];
  __syncthreads();
  #pragma unroll
  for (int j = 0; j < 32; j += 8) out[(size_t)(c0 + ty + j) * R + r0 + tx] = f2bf(t[tx][ty + j]);
}

// ---------------------------------------------------------------------------
// FUSED cdist + QKV GEMM (both K=512, independent, share the MFMA main loop).
// 128x128 tile, BK=64, 2-phase LDS dbuf (R12/R14-proven operating point).
// blocks [0,544): triangular cdist (136 upper-tri tiles x 4 batches);
// blocks [544,1312): fused QKV projection (12 x 64 tiles), 3-way bias.
//   q/k tiles (bx<8): normal row-major store into qkv.
//   v tiles  (bx>=8): epilogue LDS transpose -> write vT (b,h,dh,l) directly;
//   the v-slice of qkv is never written (nothing reads it).
__global__ __launch_bounds__(256) void gemm_cq(
    const unsigned short* __restrict__ xbf,
    const unsigned short* __restrict__ wqkvT,
    const float* __restrict__ bq, const float* __restrict__ bk,
    const float* __restrict__ bv,
    unsigned short* __restrict__ cdm, unsigned short* __restrict__ qkv,
    unsigned short* __restrict__ vT,
    const float* __restrict__ sq, float* __restrict__ rmax,
    const float* __restrict__ mask)
{
  const int bid = blockIdx.x;
  const bool isc = bid < 544;
  const unsigned short *Ap, *Bp;
  int m0, n0, bxx = 0, byy = 0, zb = 0;
  if (isc){
    zb = bid / 136;
    int tt = bid - zb * 136, byv = 0;
    while (tt >= 16 - byv){ tt -= 16 - byv; byv++; }
    byy = byv; bxx = byv + tt;
    m0 = byy * 128; n0 = bxx * 128;
    Ap = xbf + (size_t)zb * Ll * Dd; Bp = Ap;
  } else {
    int t = bid - 544;
    bxx = t % 12; byy = t / 12;
    m0 = byy * 128; n0 = bxx * 128;
    Ap = xbf; Bp = wqkvT;
  }
  const int tid = threadIdx.x, w = tid >> 6, l = tid & 63;
  const int wm = w >> 1, wn = w & 1;
  __shared__ unsigned short lA[2][128 * 64];
  __shared__ unsigned short lB[2][128 * 64];
  f32x4 acc[4][4];
  const f32x4 z4 = {0.f, 0.f, 0.f, 0.f};
  #pragma unroll
  for (int i = 0; i < 4; i++){
    #pragma unroll
    for (int j = 0; j < 4; j++) acc[i][j] = z4;
  }
  const int srow = w * 8 + (l >> 3);
  const int sc = l & 7;

  // prologue: stage k-tile 0 (K = 512 for both modes)
  #pragma unroll
  for (int j = 0; j < 4; j++){
    int row = j * 32 + srow;
    gload16(Ap + (size_t)(m0 + row) * Dd + ((sc ^ (row & 7)) << 3),
            &lA[0][0] + j * 2048 + w * 512);
    gload16(Bp + (size_t)(n0 + row) * Dd + ((sc ^ (row & 7)) << 3),
            &lB[0][0] + j * 2048 + w * 512);
  }
  __syncthreads();

  int cur = 0;
  for (int k0 = 0; k0 < Dd; k0 += 64, cur ^= 1){
    if (k0 + 64 < Dd){
      #pragma unroll
      for (int j = 0; j < 4; j++){
        int row = j * 32 + srow;
        gload16(Ap + (size_t)(m0 + row) * Dd + k0 + 64 + ((sc ^ (row & 7)) << 3),
                &lA[cur ^ 1][0] + j * 2048 + w * 512);
        gload16(Bp + (size_t)(n0 + row) * Dd + k0 + 64 + ((sc ^ (row & 7)) << 3),
                &lB[cur ^ 1][0] + j * 2048 + w * 512);
      }
    }
    bf16x8 af[4][2], bvv[4][2];
    #pragma unroll
    for (int kk = 0; kk < 2; kk++){
      #pragma unroll
      for (int f = 0; f < 4; f++){
        int ra = wm * 64 + f * 16 + (l & 15);
        af[f][kk] = *(const bf16x8*)((const char*)&lA[cur][0] + ra * 128 +
                      (((kk * 4 + (l >> 4)) ^ (ra & 7)) << 4));
        int rb = wn * 64 + f * 16 + (l & 15);
        bvv[f][kk] = *(const bf16x8*)((const char*)&lB[cur][0] + rb * 128 +
                      (((kk * 4 + (l >> 4)) ^ (rb & 7)) << 4));
      }
    }
    #pragma unroll
    for (int mf = 0; mf < 4; mf++){
      #pragma unroll
      for (int nf = 0; nf < 4; nf++){
        #pragma unroll
        for (int kk = 0; kk < 2; kk++)
          acc[mf][nf] = mfma16(af[mf][kk], bvv[nf][kk], acc[mf][nf]);
      }
    }
    __syncthreads();
  }

  if (isc){
    unsigned short* outb = cdm + (size_t)zb * Ll * Ll;
    const float* sqz = sq + zb * Ll;
    const float* mkz = mask + zb * Ll;
    float* rmz = rmax + zb * Ll;
    float sqc[4], mkc[4];
    #pragma unroll
    for (int nf = 0; nf < 4; nf++){
      int col = n0 + wn * 64 + nf * 16 + (l & 15);
      sqc[nf] = sqz[col]; mkc[nf] = mkz[col];
    }
    #pragma unroll
    for (int mf = 0; mf < 4; mf++){
      #pragma unroll
      for (int r = 0; r < 4; r++){
        int row = m0 + wm * 64 + mf * 16 + (l >> 4) * 4 + r;
        float sqi = sqz[row], mi = mkz[row];
        #pragma unroll
        for (int nf = 0; nf < 4; nf++){
          float d2 = sqi + sqc[nf] - 2.f * acc[mf][nf][r];
          acc[mf][nf][r] = sqrtf(fmaxf(d2, 0.f)) * (mi * mkc[nf]) * LOG2E + 8.f;
        }
      }
    }
    #pragma unroll
    for (int mf = 0; mf < 4; mf++){
      #pragma unroll
      for (int r = 0; r < 4; r++){
        int row = m0 + wm * 64 + mf * 16 + (l >> 4) * 4 + r;
        float rm = 0.f;
        #pragma unroll
        for (int nf = 0; nf < 4; nf++){
          int col = n0 + wn * 64 + nf * 16 + (l & 15);
          outb[(size_t)row * Ll + col] = f2bf(acc[mf][nf][r]);
          rm = fmaxf(rm, acc[mf][nf][r]);
        }
        #pragma unroll
        for (int t = 1; t < 16; t <<= 1) rm = fmaxf(rm, __shfl_xor(rm, t, 64));
        if ((l & 15) == 0) atomicMax((int*)(rmz + row), __float_as_int(rm));
      }
    }
    if (bxx != byy){
      #pragma unroll
      for (int nf = 0; nf < 4; nf++){
        int col = n0 + wn * 64 + nf * 16 + (l & 15);
        float cm = 0.f;
        #pragma unroll
        for (int mf = 0; mf < 4; mf++){
          uint2 pk2;
          pk2.x = (unsigned)f2bf(acc[mf][nf][0]) | ((unsigned)f2bf(acc[mf][nf][1]) << 16);
          pk2.y = (unsigned)f2bf(acc[mf][nf][2]) | ((unsigned)f2bf(acc[mf][nf][3]) << 16);
          int rowb = m0 + wm * 64 + mf * 16 + (l >> 4) * 4;
          *(uint2*)(outb + (size_t)col * Ll + rowb) = pk2;
          cm = fmaxf(cm, fmaxf(fmaxf(acc[mf][nf][0], acc[mf][nf][1]),
                               fmaxf(acc[mf][nf][2], acc[mf][nf][3])));
        }
        cm = fmaxf(cm, __shfl_xor(cm, 16, 64));
        cm = fmaxf(cm, __shfl_xor(cm, 32, 64));
        if ((l >> 4) == 0) atomicMax((int*)(rmz + col), __float_as_int(cm));
      }
    }
  } else if (bxx >= 8){
    // ---- v-projection blocks: bias + LDS transpose -> vT (b,h,dh,l) ----
    unsigned short* tile = &lA[0][0];   // 32KB, main loop done (post-barrier)
    const int lg = l >> 4, ql = l & 15;
    #pragma unroll
    for (int nf = 0; nf < 4; nf++){
      int cl = wn * 64 + nf * 16 + ql;           // local v-col in [0,128)
      float bvl = bv[(n0 - 1024 + cl) & 511];
      #pragma unroll
      for (int mf = 0; mf < 4; mf++){
        int rl = wm * 64 + mf * 16 + lg * 4;     // local l-row granule (4 rows)
        uint2 pk2;
        pk2.x = (unsigned)f2bf(acc[mf][nf][0] + bvl) |
                ((unsigned)f2bf(acc[mf][nf][1] + bvl) << 16);
        pk2.y = (unsigned)f2bf(acc[mf][nf][2] + bvl) |
                ((unsigned)f2bf(acc[mf][nf][3] + bvl) << 16);
        *(uint2*)((char*)tile + cl * 256 + ((rl * 2) ^ ((cl & 15) << 3))) = pk2;
      }
    }
    __syncthreads();
    // read 64 l-contiguous values per thread, write coalesced 128B runs
    int col_t = tid >> 1, half = tid & 1;
    int bb = m0 >> 11, m0l = m0 & 2047;
    int gv = (n0 - 1024) + col_t;                // global v-dim in [0,512)
    unsigned short* dst = vT +
        (((size_t)(bb * Hh) + (gv >> 6)) * DHd + (gv & 63)) * Ll + m0l + half * 64;
    #pragma unroll
    for (int j4 = 0; j4 < 8; j4++){
      uint2 lo = *(uint2*)((char*)tile + col_t * 256 +
                  ((half * 128 + j4 * 16) ^ ((col_t & 15) << 3)));
      uint2 hi = *(uint2*)((char*)tile + col_t * 256 +
                  ((half * 128 + j4 * 16 + 8) ^ ((col_t & 15) << 3)));
      uint4 o4; o4.x = lo.x; o4.y = lo.y; o4.z = hi.x; o4.w = hi.y;
      *(uint4*)(dst + j4 * 8) = o4;
    }
  } else {
    #pragma unroll
    for (int mf = 0; mf < 4; mf++){
      #pragma unroll
      for (int r = 0; r < 4; r++){
        int row = m0 + wm * 64 + mf * 16 + (l >> 4) * 4 + r;
        #pragma unroll
        for (int nf = 0; nf < 4; nf++){
          int col = n0 + wn * 64 + nf * 16 + (l & 15);
          const float* bp = col < 512 ? bq : bk;
          float v = acc[mf][nf][r] + bp[col & 511];
          qkv[(size_t)row * 1536 + col] = f2bf(v);
        }
      }
    }
  }
}

// ---------------------------------------------------------------------------
// 128x128x64 bf16 MFMA GEMM, B transposed (N,K) row-major, 2-phase LDS dbuf.
// MODE 3: relu(+bias) -> bf16
// MODE 6: SPLIT-K x2 (z = k-half): bf16 partials -> outb + z*M*N
// MODE 7: +bias +extra(f32) -> bf16 (attn out-proj + residual)
template<int MODE>
__global__ __launch_bounds__(256) void gemm_bt(
    const unsigned short* __restrict__ A,
    const unsigned short* __restrict__ Bt,
    int M, int N, int K,
    const float* __restrict__ bias,
    const float* __restrict__ extra,
    unsigned short* __restrict__ outb)
{
  int m0 = blockIdx.y * 128, n0 = blockIdx.x * 128;
  if (MODE == 6){                      // split-K: offset into the k-half
    int z = blockIdx.z;
    A    += (size_t)z * (K >> 1);
    Bt   += (size_t)z * (K >> 1);
    outb += (size_t)z * (size_t)M * N;
  }
  const int KL = (MODE == 6) ? (K >> 1) : K;
  const int tid = threadIdx.x, w = tid >> 6, l = tid & 63;
  const int wm = w >> 1, wn = w & 1;
  __shared__ unsigned short lA[2][128 * 64];
  __shared__ unsigned short lB[2][128 * 64];
  f32x4 acc[4][4];
  const f32x4 z4 = {0.f, 0.f, 0.f, 0.f};
  #pragma unroll
  for (int i = 0; i < 4; i++){
    #pragma unroll
    for (int j = 0; j < 4; j++) acc[i][j] = z4;
  }
  const int srow = w * 8 + (l >> 3);
  const int sc = l & 7;

  #pragma unroll
  for (int j = 0; j < 4; j++){
    int row = j * 32 + srow;
    gload16(A + (size_t)(m0 + row) * K + ((sc ^ (row & 7)) << 3),
            &lA[0][0] + j * 2048 + w * 512);
    gload16(Bt + (size_t)(n0 + row) * K + ((sc ^ (row & 7)) << 3),
            &lB[0][0] + j * 2048 + w * 512);
  }
  __syncthreads();

  int cur = 0;
  for (int k0 = 0; k0 < KL; k0 += 64, cur ^= 1){
    if (k0 + 64 < KL){
      #pragma unroll
      for (int j = 0; j < 4; j++){
        int row = j * 32 + srow;
        gload16(A + (size_t)(m0 + row) * K + k0 + 64 + ((sc ^ (row & 7)) << 3),
                &lA[cur ^ 1][0] + j * 2048 + w * 512);
        gload16(Bt + (size_t)(n0 + row) * K + k0 + 64 + ((sc ^ (row & 7)) << 3),
                &lB[cur ^ 1][0] + j * 2048 + w * 512);
      }
    }
    bf16x8 af[4][2], bv[4][2];
    #pragma unroll
    for (int kk = 0; kk < 2; kk++){
      #pragma unroll
      for (int f = 0; f < 4; f++){
        int ra = wm * 64 + f * 16 + (l & 15);
        af[f][kk] = *(const bf16x8*)((const char*)&lA[cur][0] + ra * 128 +
                      (((kk * 4 + (l >> 4)) ^ (ra & 7)) << 4));
        int rb = wn * 64 + f * 16 + (l & 15);
        bv[f][kk] = *(const bf16x8*)((const char*)&lB[cur][0] + rb * 128 +
                      (((kk * 4 + (l >> 4)) ^ (rb & 7)) << 4));
      }
    }
    #pragma unroll
    for (int mf = 0; mf < 4; mf++){
      #pragma unroll
      for (int nf = 0; nf < 4; nf++){
        #pragma unroll
        for (int kk = 0; kk < 2; kk++)
          acc[mf][nf] = mfma16(af[mf][kk], bv[nf][kk], acc[mf][nf]);
      }
    }
    __syncthreads();
  }

  #pragma unroll
  for (int mf = 0; mf < 4; mf++){
    #pragma unroll
    for (int r = 0; r < 4; r++){
      int row = m0 + wm * 64 + mf * 16 + (l >> 4) * 4 + r;
      #pragma unroll
      for (int nf = 0; nf < 4; nf++){
        int col = n0 + wn * 64 + nf * 16 + (l & 15);
        if (MODE == 6){
          outb[(size_t)row * N + col] = f2bf(acc[mf][nf][r]);
        } else if (MODE == 3){
          float v = acc[mf][nf][r] + bias[col];
          outb[(size_t)row * N + col] = f2bf(fmaxf(v, 0.f));
        } else {  // MODE 7
          float v = acc[mf][nf][r] + bias[col] + extra[(size_t)row * N + col];
          outb[(size_t)row * N + col] = f2bf(v);
        }
      }
    }
  }
}

// ---------------------------------------------------------------------------
// flash attention, SWAPPED QK^T, FIXED-m exp2 softmax, QBLK=64 (R12-proven).
// grid (L/64, H, B) = 1024 blocks, block 256 (4 waves x 16 q-rows).
// LDS 40KB -> 4 blocks/CU.
__global__ __launch_bounds__(256, 4) void flash_attn(
    const unsigned short* __restrict__ qkv,
    const unsigned short* __restrict__ vT,
    const unsigned short* __restrict__ cdm,   // cd*LOG2E + 8
    const float* __restrict__ rmax,           // max_k of stored cdm
    unsigned short* __restrict__ y)
{
  const int b = blockIdx.z, h = blockIdx.y, q0 = blockIdx.x * 64;
  const int tid = threadIdx.x, w = tid >> 6, l = tid & 63;
  const int ql = l & 15, lg = l >> 4;
  __shared__ unsigned short QPs[64 * 64];    //  8KB: Q staging; reused as P
  __shared__ unsigned short Ks[2][64 * 64];  // 16KB dbuf
  __shared__ unsigned short Vs[2][64 * 64];  // 16KB dbuf

  const int srow = w * 8 + (l >> 3);
  const int sc = l & 7;
  const unsigned short* kbase = qkv + (size_t)b * Ll * 1536 + 512 + h * DHd;
  const unsigned short* vbase = vT + (size_t)(b * Hh + h) * DHd * Ll;

  // prologue: stage Q + tile 0 of K/V
  #pragma unroll
  for (int j = 0; j < 2; j++){
    int row = j * 32 + srow;
    gload16(qkv + (size_t)(b * Ll + q0 + row) * 1536 + h * DHd + ((sc ^ (row & 7)) << 3),
            QPs + j * 2048 + w * 512);
    gload16(kbase + (size_t)row * 1536 + ((sc ^ (row & 7)) << 3),
            &Ks[0][0] + j * 2048 + w * 512);
    gload16(vbase + (size_t)row * Ll + ((sc ^ (row & 7)) << 3),
            &Vs[0][0] + j * 2048 + w * 512);
  }

  const int qg = q0 + w * 16 + ql;                 // this lane's q-row
  const float rmx8 = rmax[b * Ll + qg] - 8.f;      // diag correction
  const unsigned short* cdrow = cdm + (size_t)(b * Ll + qg) * Ll;

  // register-prefetch cd bias for tile 0
  uint2 cdn[4];
  #pragma unroll
  for (int nf = 0; nf < 4; nf++)
    cdn[nf] = *(const uint2*)(cdrow + nf * 16 + lg * 4);

  f32x4 o[4];
  const f32x4 z4 = {0.f, 0.f, 0.f, 0.f};
  #pragma unroll
  for (int nf = 0; nf < 4; nf++) o[nf] = z4;
  float lsum = 0.f;

  __syncthreads();   // Q + tile 0 resident

  // hoist Q B-fragments (constant over k-loop); QPs region free afterwards
  bf16x8 qa[2];
  #pragma unroll
  for (int kk = 0; kk < 2; kk++){
    int ra = w * 16 + ql;
    qa[kk] = *(const bf16x8*)((const char*)QPs + ra * 128 +
               (((kk * 4 + lg) ^ (ql & 7)) << 4));
  }

  const int NT = Ll / 64;
  for (int t = 0; t < NT; ++t){
    const int k0 = t * 64;
    const int cur = t & 1;

    uint2 cdc[4];                       // this tile's bias (prefetched last tile)
    #pragma unroll
    for (int nf = 0; nf < 4; nf++) cdc[nf] = cdn[nf];

    if (t + 1 < NT){
      const int kn = k0 + 64;
      #pragma unroll
      for (int nf = 0; nf < 4; nf++)    // prefetch next tile's bias
        cdn[nf] = *(const uint2*)(cdrow + kn + nf * 16 + lg * 4);
      #pragma unroll
      for (int j = 0; j < 2; j++){      // stage next K/V (overlaps compute)
        int row = j * 32 + srow;
        gload16(kbase + (size_t)(kn + row) * 1536 + ((sc ^ (row & 7)) << 3),
                &Ks[cur ^ 1][0] + j * 2048 + w * 512);
        gload16(vbase + (size_t)row * Ll + kn + ((sc ^ (row & 7)) << 3),
                &Vs[cur ^ 1][0] + j * 2048 + w * 512);
      }
    }

    // S^T = K Q^T : lane gets q = w*16+ql, k = nf*16 + lg*4 + r
    f32x4 s[4];
    #pragma unroll
    for (int nf = 0; nf < 4; nf++){
      s[nf] = z4;
      #pragma unroll
      for (int kk = 0; kk < 2; kk++){
        int rb = nf * 16 + ql;
        bf16x8 kb = *(const bf16x8*)((const char*)Ks[cur] + rb * 128 +
                      (((kk * 4 + lg) ^ (ql & 7)) << 4));
        s[nf] = mfma16(kb, qa[kk], s[nf]);
      }
    }

    // ---- fixed-m softmax: p = 2^(qk*c - cdm'), no running max ----
    float sv[16];
    #pragma unroll
    for (int nf = 0; nf < 4; nf++){
      float c0 = __uint_as_float(cdc[nf].x << 16);
      float c1 = __uint_as_float(cdc[nf].x & 0xffff0000u);
      float c2 = __uint_as_float(cdc[nf].y << 16);
      float c3 = __uint_as_float(cdc[nf].y & 0xffff0000u);
      sv[nf * 4 + 0] = fmaf(s[nf][0], 0.125f * LOG2E, -c0);
      sv[nf * 4 + 1] = fmaf(s[nf][1], 0.125f * LOG2E, -c1);
      sv[nf * 4 + 2] = fmaf(s[nf][2], 0.125f * LOG2E, -c2);
      sv[nf * 4 + 3] = fmaf(s[nf][3], 0.125f * LOG2E, -c3);
    }
    if (k0 == q0){            // diagonal tile: subtract (rmax_stored - 8)
      #pragma unroll
      for (int nf = 0; nf < 4; nf++) if (nf == w){
        #pragma unroll
        for (int r = 0; r < 4; r++)
          if (lg * 4 + r == ql) sv[nf * 4 + r] -= rmx8;
      }
    }

    float p[16], ps = 0.f;
    #pragma unroll
    for (int i = 0; i < 16; i++){ p[i] = exp2_hw(sv[i]); ps += p[i]; }
    lsum += ps;                         // per-lane partial; reduce at end

    // P -> LDS (wave-private region of QPs), packed b64 per nf
    #pragma unroll
    for (int nf = 0; nf < 4; nf++){
      unsigned d0, d1;
      asm("v_cvt_pk_bf16_f32 %0, %1, %2" : "=v"(d0) : "v"(p[nf*4+0]), "v"(p[nf*4+1]));
      asm("v_cvt_pk_bf16_f32 %0, %1, %2" : "=v"(d1) : "v"(p[nf*4+2]), "v"(p[nf*4+3]));
      uint2 pk2; pk2.x = d0; pk2.y = d1;
      *(uint2*)((char*)QPs + w * 2048 + ql * 128 +
                ((nf * 32 + lg * 8) ^ ((ql & 7) << 4))) = pk2;
    }

    // PV: A = P (rows = q), B = V (cols = dh)
    bf16x8 pa[2];
    #pragma unroll
    for (int kk = 0; kk < 2; kk++)
      pa[kk] = *(const bf16x8*)((const char*)QPs + w * 2048 + ql * 128 +
                 ((((kk * 4 + lg)) ^ (ql & 7)) << 4));
    #pragma unroll
    for (int nf = 0; nf < 4; nf++){
      #pragma unroll
      for (int kk = 0; kk < 2; kk++){
        int rv = nf * 16 + ql;
        bf16x8 vb = *(const bf16x8*)((const char*)Vs[cur] + rv * 128 +
                      (((kk * 4 + lg) ^ (ql & 7)) << 4));
        o[nf] = mfma16(pa[kk], vb, o[nf]);
      }
    }
    __syncthreads();   // staged loads drained; buffers safe to swap
  }

  // epilogue: O rows are q = q0 + w*16 + lg*4 + r; reduce lsum across lg now
  float ltot = lsum;
  ltot += __shfl_xor(ltot, 16, 64);
  ltot += __shfl_xor(ltot, 32, 64);
  float lf[4];
  #pragma unroll
  for (int r = 0; r < 4; r++)
    lf[r] = __shfl(ltot, (l & 48) | (lg * 4 + r), 64);
  #pragma unroll
  for (int nf = 0; nf < 4; nf++){
    #pragma unroll
    for (int r = 0; r < 4; r++){
      int qo = q0 + w * 16 + lg * 4 + r;
      float v = o[nf][r] / lf[r];
      y[(size_t)(b * Ll + qo) * Dd + h * DHd + nf * 16 + ql] = f2bf(v);
    }
  }
}

// ---------------------------------------------------------------------------
// layernorm over D=512, bf16 input -> bf16 out.  grid = B*L, block 256.
__global__ __launch_bounds__(256) void ln_kernel(const unsigned short* __restrict__ in,
                                                 const float* __restrict__ g,
                                                 const float* __restrict__ bt,
                                                 unsigned short* __restrict__ outb){
  int row = blockIdx.x, tid = threadIdx.x;
  unsigned u = ((const unsigned*)(in + (size_t)row * Dd))[tid];
  float vx = __uint_as_float(u << 16);
  float vy = __uint_as_float(u & 0xffff0000u);
  float s = vx + vy, s2 = vx * vx + vy * vy;
  #pragma unroll
  for (int t = 1; t < 64; t <<= 1){ s += __shfl_xor(s, t, 64); s2 += __shfl_xor(s2, t, 64); }
  __shared__ float red[8];
  if ((tid & 63) == 0){ red[tid >> 6] = s; red[4 + (tid >> 6)] = s2; }
  __syncthreads();
  float S  = red[0] + red[1] + red[2] + red[3];
  float S2 = red[4] + red[5] + red[6] + red[7];
  float mu = S * (1.f / 512.f);
  float var = fmaxf(S2 * (1.f / 512.f) - mu * mu, 0.f);
  float rs = rsqrtf(var + 1e-5f);
  int c = tid * 2;
  float o0 = (vx - mu) * rs * g[c] + bt[c];
  float o1 = (vy - mu) * rs * g[c + 1] + bt[c + 1];
  ((unsigned*)(outb + (size_t)row * Dd))[tid] =
      (unsigned)f2bf(o0) | ((unsigned)f2bf(o1) << 16);
}

// ---------------------------------------------------------------------------
// layernorm over (p0 + p1 + bias + extra_bf16): combines FFN2 bf16 split-K
// partials, adds the bf16 residual (LN1 out), then LN.  grid = B*L, block 256.
__global__ __launch_bounds__(256) void ln2p_kernel(
    const unsigned short* __restrict__ p01,     // [2][M][512] bf16 FFN2 partials
    const float* __restrict__ bias,
    const unsigned short* __restrict__ extra,   // residual, bf16 (LN1 out)
    const float* __restrict__ g, const float* __restrict__ bt,
    float* __restrict__ outf)
{
  int row = blockIdx.x, tid = threadIdx.x;
  unsigned u0 = ((const unsigned*)(p01 + (size_t)row * Dd))[tid];
  unsigned u1 = ((const unsigned*)(p01 + (size_t)Bb * Ll * Dd + (size_t)row * Dd))[tid];
  unsigned ex = ((const unsigned*)(extra + (size_t)row * Dd))[tid];
  float a0x = __uint_as_float(u0 << 16),        a0y = __uint_as_float(u0 & 0xffff0000u);
  float a1x = __uint_as_float(u1 << 16),        a1y = __uint_as_float(u1 & 0xffff0000u);
  float ex0 = __uint_as_float(ex << 16),        ex1 = __uint_as_float(ex & 0xffff0000u);
  int c = tid * 2;
  float vx = a0x + a1x + bias[c]     + ex0;
  float vy = a0y + a1y + bias[c + 1] + ex1;
  float s = vx + vy, s2 = vx * vx + vy * vy;
  #pragma unroll
  for (int t = 1; t < 64; t <<= 1){ s += __shfl_xor(s, t, 64); s2 += __shfl_xor(s2, t, 64); }
  __shared__ float red[8];
  if ((tid & 63) == 0){ red[tid >> 6] = s; red[4 + (tid >> 6)] = s2; }
  __syncthreads();
  float S  = red[0] + red[1] + red[2] + red[3];
  float S2 = red[4] + red[5] + red[6] + red[7];
  float mu = S * (1.f / 512.f);
  float var = fmaxf(S2 * (1.f / 512.f) - mu * mu, 0.f);
  float rs = rsqrtf(var + 1e-5f);
  float o0 = (vx - mu) * rs * g[c] + bt[c];
  float o1 = (vy - mu) * rs * g[c + 1] + bt[c + 1];
  float2 ov; ov.x = o0; ov.y = o1;
  ((float2*)(outf + (size_t)row * Dd))[tid] = ov;
}

// ---------------------------------------------------------------------------
extern "C" void kernel_launch(void* const* d_in, const int* in_sizes, int n_in,
                              void* d_out, int out_size, void* d_ws, size_t ws_size,
                              hipStream_t stream){
  const float* x     = (const float*)d_in[0];
  const float* nmask = (const float*)d_in[1];
  const float* wq = (const float*)d_in[2];  const float* bq = (const float*)d_in[3];
  const float* wk = (const float*)d_in[4];  const float* bk = (const float*)d_in[5];
  const float* wv = (const float*)d_in[6];  const float* bv = (const float*)d_in[7];
  const float* wo = (const float*)d_in[8];  const float* bo = (const float*)d_in[9];
  const float* ln1g = (const float*)d_in[10]; const float* ln1b = (const float*)d_in[11];
  const float* w1 = (const float*)d_in[12]; const float* b1 = (const float*)d_in[13];
  const float* w2 = (const float*)d_in[14]; const float* b2 = (const float*)d_in[15];
  const float* ln2g = (const float*)d_in[16]; const float* ln2b = (const float*)d_in[17];
  float* outp = (float*)d_out;
  char* ws = (char*)d_ws;

  // workspace layout (bytes)
  unsigned short* xbf   = (unsigned short*)(ws + 0);          //  8 MB
  float* sq   = (float*)(ws + 8388608);                       //  32 KB
  float* rmax = (float*)(ws + 8421376);                       //  32 KB
  unsigned short* wqkvT = (unsigned short*)(ws + 8454144);    //  1.5 MB (1536 x 512)
  unsigned short* woT   = (unsigned short*)(ws + 10027008);   //  512 KB
  unsigned short* w1T   = (unsigned short*)(ws + 10551296);   //  2 MB
  unsigned short* w2T   = (unsigned short*)(ws + 12648448);   //  2 MB
  unsigned short* cdm   = (unsigned short*)(ws + 14745600);   // 32 MB (later reused as h1)
  unsigned short* qkv   = (unsigned short*)(ws + 48300032);   // 24 MB (b,l,1536; v-slice unused)
  unsigned short* vT    = (unsigned short*)(ws + 73465856);   //  8 MB
  unsigned short* yb    = (unsigned short*)(ws + 81854464);   //  8 MB
  unsigned short* resb  = (unsigned short*)(ws + 90243072);   //  8 MB (attn residual, bf16)
  unsigned short* p01   = (unsigned short*)(ws + 98631680);   // 16 MB FFN2 bf16 partials
  unsigned short* h1  = cdm;    // reuse (cdist dead after attention)
  unsigned short* Xbf = qkv;    // reuse (qkv dead after attention); LN1 out bf16

  prep_all<<<3072 + Bb * Ll, 256, 0, stream>>>(x, wq, wk, wv, wo, w1, w2,
                                               xbf, sq, rmax, wqkvT, woT, w1T, w2T);

  // FUSED: triangular cdist (0..543) + QKV proj (544..1311, v written to vT)
  gemm_cq<<<1312, 256, 0, stream>>>(xbf, wqkvT, bq, bk, bv,
                                    cdm, qkv, vT, sq, rmax, nmask);

  flash_attn<<<dim3(Ll / 64, Hh, Bb), 256, 0, stream>>>(qkv, vT, cdm, rmax, yb);

  // out projection + residual -> resb (bf16)
  gemm_bt<7><<<dim3(4, 64, 1), 256, 0, stream>>>(yb, woT, Bb * Ll, Dd, Dd,
      bo, x, resb);

  // LN1 (bf16 in) -> bf16 out (residual for LN2)
  ln_kernel<<<Bb * Ll, 256, 0, stream>>>(resb, ln1g, ln1b, Xbf);

  // FFN
  gemm_bt<3><<<dim3(16, 64, 1), 256, 0, stream>>>(Xbf, w1T, Bb * Ll, 4 * Dd, Dd,
      b1, nullptr, h1);
  // FFN2 split-K x2 -> bf16 partials in p01 (p0 at 0, p1 at +M*N)
  gemm_bt<6><<<dim3(4, 64, 2), 256, 0, stream>>>(h1, w2T, Bb * Ll, Dd, 4 * Dd,
      nullptr, nullptr, p01);

  ln2p_kernel<<<Bb * Ll, 256, 0, stream>>>(p01, b2, Xbf, ln2g, ln2b, outp);
}

// Round 17
// 219.574 us; speedup vs baseline: 1.1178x; 1.0010x over previous
//
#include <hip/hip_runtime.h>
#include <stdint.h>

#define GAS __attribute__((address_space(1)))
#define LAS __attribute__((address_space(3)))

typedef __attribute__((ext_vector_type(8))) __bf16 bf16x8;
typedef __attribute__((ext_vector_type(4))) float f32x4;

static constexpr int Bb = 4, Ll = 2048, Dd = 512, Hh = 8, DHd = 64;
static constexpr float LOG2E = 1.4426950408889634f;

__device__ __forceinline__ unsigned short f2bf(float f){
  unsigned u = __float_as_uint(f);
  u += 0x7fffu + ((u >> 16) & 1u);           // round-to-nearest-even
  return (unsigned short)(u >> 16);
}
__device__ __forceinline__ void gload16(const void* g, void* l){
  __builtin_amdgcn_global_load_lds((const GAS void*)g, (LAS void*)l, 16, 0, 0);
}
__device__ __forceinline__ f32x4 mfma16(bf16x8 a, bf16x8 b, f32x4 c){
  return __builtin_amdgcn_mfma_f32_16x16x32_bf16(a, b, c, 0, 0, 0);
}
__device__ __forceinline__ float exp2_hw(float x){   // v_exp_f32 = 2^x
  float r; asm("v_exp_f32 %0, %1" : "=v"(r) : "v"(x)); return r;
}

// ---------------------------------------------------------------------------
// fused prep: blocks [0,3072) = weight transposes (f32 (R,C) -> bf16 (C,R));
// blocks [3072, 3072+8192) = per-row sum-of-squares + x f32->bf16 cast + rmax=0.
__global__ __launch_bounds__(256) void prep_all(
    const float* __restrict__ x,
    const float* __restrict__ wq, const float* __restrict__ wk,
    const float* __restrict__ wv, const float* __restrict__ wo,
    const float* __restrict__ w1, const float* __restrict__ w2,
    unsigned short* __restrict__ xbf, float* __restrict__ sq,
    float* __restrict__ rmax,
    unsigned short* __restrict__ wqkvT, unsigned short* __restrict__ woT,
    unsigned short* __restrict__ w1T, unsigned short* __restrict__ w2T)
{
  __shared__ float t[32][33];
  __shared__ float red[4];
  int bid = blockIdx.x;
  if (bid >= 3072){
    // ---- sumsq + cast + rmax zero ----
    int row = bid - 3072, tid = threadIdx.x;
    float2 v = ((const float2*)(x + (size_t)row * Dd))[tid];
    ((unsigned*)(xbf + (size_t)row * Dd))[tid] =
        (unsigned)f2bf(v.x) | ((unsigned)f2bf(v.y) << 16);
    float s2 = v.x * v.x + v.y * v.y;
    #pragma unroll
    for (int s = 1; s < 64; s <<= 1) s2 += __shfl_xor(s2, s, 64);
    if ((tid & 63) == 0) red[tid >> 6] = s2;
    __syncthreads();
    if (tid == 0){
      sq[row] = red[0] + red[1] + red[2] + red[3];
      rmax[row] = 0.f;
    }
    return;
  }
  // ---- weight transpose ----
  const float* in; unsigned short* out; int R, C, bx, by;
  if (bid < 1024){
    int s = bid >> 8, tt = bid & 255;
    in  = s == 0 ? wq : s == 1 ? wk : s == 2 ? wv : wo;
    out = s == 3 ? woT : wqkvT + s * 512 * 512;
    R = 512; C = 512; bx = tt & 15; by = tt >> 4;
  } else if (bid < 2048){
    int tt = bid - 1024; in = w1; out = w1T; R = 512; C = 2048; bx = tt & 63; by = tt >> 6;
  } else {
    int tt = bid - 2048; in = w2; out = w2T; R = 2048; C = 512; bx = tt & 15; by = tt >> 4;
  }
  int tx = threadIdx.x & 31, ty = threadIdx.x >> 5;
  int c0 = bx * 32, r0 = by * 32;
  #pragma unroll
  for (int j = 0; j < 32; j += 8) t[ty + j][tx] = in[(size_t)(r0 + ty + j) * C + c0 + tx];
  __syncthreads();
  #pragma unroll
  for (int j = 0; j < 32; j += 8) out[(size_t)(c0 + ty + j) * R + r0 + tx] = f2bf(t[tx][ty + j]);
}

// ---------------------------------------------------------------------------
// FUSED cdist + QKV GEMM (both K=512, independent, share the MFMA main loop).
// 128x128 tile, BK=64, 2-phase LDS dbuf (R12/R14-proven operating point).
// blocks [0,544): triangular cdist (136 upper-tri tiles x 4 batches);
// blocks [544,1312): fused QKV projection (12 x 64 tiles), 3-way bias.
//   q/k tiles (bx<8): normal row-major store into qkv.
//   v tiles  (bx>=8): epilogue LDS transpose -> write vT (b,h,dh,l) directly;
//   the v-slice of qkv is never written (nothing reads it).
__global__ __launch_bounds__(256) void gemm_cq(
    const unsigned short* __restrict__ xbf,
    const unsigned short* __restrict__ wqkvT,
    const float* __restrict__ bq, const float* __restrict__ bk,
    const float* __restrict__ bv,
    unsigned short* __restrict__ cdm, unsigned short* __restrict__ qkv,
    unsigned short* __restrict__ vT,
    const float* __restrict__ sq, float* __restrict__ rmax,
    const float* __restrict__ mask)
{
  const int bid = blockIdx.x;
  const bool isc = bid < 544;
  const unsigned short *Ap, *Bp;
  int m0, n0, bxx = 0, byy = 0, zb = 0;
  if (isc){
    zb = bid / 136;
    int tt = bid - zb * 136, byv = 0;
    while (tt >= 16 - byv){ tt -= 16 - byv; byv++; }
    byy = byv; bxx = byv + tt;
    m0 = byy * 128; n0 = bxx * 128;
    Ap = xbf + (size_t)zb * Ll * Dd; Bp = Ap;
  } else {
    int t = bid - 544;
    bxx = t % 12; byy = t / 12;
    m0 = byy * 128; n0 = bxx * 128;
    Ap = xbf; Bp = wqkvT;
  }
  const int tid = threadIdx.x, w = tid >> 6, l = tid & 63;
  const int wm = w >> 1, wn = w & 1;
  __shared__ unsigned short lA[2][128 * 64];
  __shared__ unsigned short lB[2][128 * 64];
  f32x4 acc[4][4];
  const f32x4 z4 = {0.f, 0.f, 0.f, 0.f};
  #pragma unroll
  for (int i = 0; i < 4; i++){
    #pragma unroll
    for (int j = 0; j < 4; j++) acc[i][j] = z4;
  }
  const int srow = w * 8 + (l >> 3);
  const int sc = l & 7;

  // prologue: stage k-tile 0 (K = 512 for both modes)
  #pragma unroll
  for (int j = 0; j < 4; j++){
    int row = j * 32 + srow;
    gload16(Ap + (size_t)(m0 + row) * Dd + ((sc ^ (row & 7)) << 3),
            &lA[0][0] + j * 2048 + w * 512);
    gload16(Bp + (size_t)(n0 + row) * Dd + ((sc ^ (row & 7)) << 3),
            &lB[0][0] + j * 2048 + w * 512);
  }
  __syncthreads();

  int cur = 0;
  for (int k0 = 0; k0 < Dd; k0 += 64, cur ^= 1){
    if (k0 + 64 < Dd){
      #pragma unroll
      for (int j = 0; j < 4; j++){
        int row = j * 32 + srow;
        gload16(Ap + (size_t)(m0 + row) * Dd + k0 + 64 + ((sc ^ (row & 7)) << 3),
                &lA[cur ^ 1][0] + j * 2048 + w * 512);
        gload16(Bp + (size_t)(n0 + row) * Dd + k0 + 64 + ((sc ^ (row & 7)) << 3),
                &lB[cur ^ 1][0] + j * 2048 + w * 512);
      }
    }
    bf16x8 af[4][2], bvv[4][2];
    #pragma unroll
    for (int kk = 0; kk < 2; kk++){
      #pragma unroll
      for (int f = 0; f < 4; f++){
        int ra = wm * 64 + f * 16 + (l & 15);
        af[f][kk] = *(const bf16x8*)((const char*)&lA[cur][0] + ra * 128 +
                      (((kk * 4 + (l >> 4)) ^ (ra & 7)) << 4));
        int rb = wn * 64 + f * 16 + (l & 15);
        bvv[f][kk] = *(const bf16x8*)((const char*)&lB[cur][0] + rb * 128 +
                      (((kk * 4 + (l >> 4)) ^ (rb & 7)) << 4));
      }
    }
    #pragma unroll
    for (int mf = 0; mf < 4; mf++){
      #pragma unroll
      for (int nf = 0; nf < 4; nf++){
        #pragma unroll
        for (int kk = 0; kk < 2; kk++)
          acc[mf][nf] = mfma16(af[mf][kk], bvv[nf][kk], acc[mf][nf]);
      }
    }
    __syncthreads();
  }

  if (isc){
    unsigned short* outb = cdm + (size_t)zb * Ll * Ll;
    const float* sqz = sq + zb * Ll;
    const float* mkz = mask + zb * Ll;
    float* rmz = rmax + zb * Ll;
    float sqc[4], mkc[4];
    #pragma unroll
    for (int nf = 0; nf < 4; nf++){
      int col = n0 + wn * 64 + nf * 16 + (l & 15);
      sqc[nf] = sqz[col]; mkc[nf] = mkz[col];
    }
    #pragma unroll
    for (int mf = 0; mf < 4; mf++){
      #pragma unroll
      for (int r = 0; r < 4; r++){
        int row = m0 + wm * 64 + mf * 16 + (l >> 4) * 4 + r;
        float sqi = sqz[row], mi = mkz[row];
        #pragma unroll
        for (int nf = 0; nf < 4; nf++){
          float d2 = sqi + sqc[nf] - 2.f * acc[mf][nf][r];
          acc[mf][nf][r] = sqrtf(fmaxf(d2, 0.f)) * (mi * mkc[nf]) * LOG2E + 8.f;
        }
      }
    }
    #pragma unroll
    for (int mf = 0; mf < 4; mf++){
      #pragma unroll
      for (int r = 0; r < 4; r++){
        int row = m0 + wm * 64 + mf * 16 + (l >> 4) * 4 + r;
        float rm = 0.f;
        #pragma unroll
        for (int nf = 0; nf < 4; nf++){
          int col = n0 + wn * 64 + nf * 16 + (l & 15);
          outb[(size_t)row * Ll + col] = f2bf(acc[mf][nf][r]);
          rm = fmaxf(rm, acc[mf][nf][r]);
        }
        #pragma unroll
        for (int t = 1; t < 16; t <<= 1) rm = fmaxf(rm, __shfl_xor(rm, t, 64));
        if ((l & 15) == 0) atomicMax((int*)(rmz + row), __float_as_int(rm));
      }
    }
    if (bxx != byy){
      #pragma unroll
      for (int nf = 0; nf < 4; nf++){
        int col = n0 + wn * 64 + nf * 16 + (l & 15);
        float cm = 0.f;
        #pragma unroll
        for (int mf = 0; mf < 4; mf++){
          uint2 pk2;
          pk2.x = (unsigned)f2bf(acc[mf][nf][0]) | ((unsigned)f2bf(acc[mf][nf][1]) << 16);
          pk2.y = (unsigned)f2bf(acc[mf][nf][2]) | ((unsigned)f2bf(acc[mf][nf][3]) << 16);
          int rowb = m0 + wm * 64 + mf * 16 + (l >> 4) * 4;
          *(uint2*)(outb + (size_t)col * Ll + rowb) = pk2;
          cm = fmaxf(cm, fmaxf(fmaxf(acc[mf][nf][0], acc[mf][nf][1]),
                               fmaxf(acc[mf][nf][2], acc[mf][nf][3])));
        }
        cm = fmaxf(cm, __shfl_xor(cm, 16, 64));
        cm = fmaxf(cm, __shfl_xor(cm, 32, 64));
        if ((l >> 4) == 0) atomicMax((int*)(rmz + col), __float_as_int(cm));
      }
    }
  } else if (bxx >= 8){
    // ---- v-projection blocks: bias + LDS transpose -> vT (b,h,dh,l) ----
    unsigned short* tile = &lA[0][0];   // 32KB, main loop done (post-barrier)
    const int lg = l >> 4, ql = l & 15;
    #pragma unroll
    for (int nf = 0; nf < 4; nf++){
      int cl = wn * 64 + nf * 16 + ql;           // local v-col in [0,128)
      float bvl = bv[(n0 - 1024 + cl) & 511];
      #pragma unroll
      for (int mf = 0; mf < 4; mf++){
        int rl = wm * 64 + mf * 16 + lg * 4;     // local l-row granule (4 rows)
        uint2 pk2;
        pk2.x = (unsigned)f2bf(acc[mf][nf][0] + bvl) |
                ((unsigned)f2bf(acc[mf][nf][1] + bvl) << 16);
        pk2.y = (unsigned)f2bf(acc[mf][nf][2] + bvl) |
                ((unsigned)f2bf(acc[mf][nf][3] + bvl) << 16);
        *(uint2*)((char*)tile + cl * 256 + ((rl * 2) ^ ((cl & 15) << 3))) = pk2;
      }
    }
    __syncthreads();
    // read 64 l-contiguous values per thread, write coalesced 128B runs
    int col_t = tid >> 1, half = tid & 1;
    int bb = m0 >> 11, m0l = m0 & 2047;
    int gv = (n0 - 1024) + col_t;                // global v-dim in [0,512)
    unsigned short* dst = vT +
        (((size_t)(bb * Hh) + (gv >> 6)) * DHd + (gv & 63)) * Ll + m0l + half * 64;
    #pragma unroll
    for (int j4 = 0; j4 < 8; j4++){
      uint2 lo = *(uint2*)((char*)tile + col_t * 256 +
                  ((half * 128 + j4 * 16) ^ ((col_t & 15) << 3)));
      uint2 hi = *(uint2*)((char*)tile + col_t * 256 +
                  ((half * 128 + j4 * 16 + 8) ^ ((col_t & 15) << 3)));
      uint4 o4; o4.x = lo.x; o4.y = lo.y; o4.z = hi.x; o4.w = hi.y;
      *(uint4*)(dst + j4 * 8) = o4;
    }
  } else {
    #pragma unroll
    for (int mf = 0; mf < 4; mf++){
      #pragma unroll
      for (int r = 0; r < 4; r++){
        int row = m0 + wm * 64 + mf * 16 + (l >> 4) * 4 + r;
        #pragma unroll
        for (int nf = 0; nf < 4; nf++){
          int col = n0 + wn * 64 + nf * 16 + (l & 15);
          const float* bp = col < 512 ? bq : bk;
          float v = acc[mf][nf][r] + bp[col & 511];
          qkv[(size_t)row * 1536 + col] = f2bf(v);
        }
      }
    }
  }
}

// ---------------------------------------------------------------------------
// 128x128x64 bf16 MFMA GEMM, B transposed (N,K) row-major, 2-phase LDS dbuf.
// MODE 3: relu(+bias) -> bf16
// MODE 6: SPLIT-K x2 (z = k-half): bf16 partials -> outb + z*M*N
// MODE 7: +bias +extra(f32) -> bf16 (attn out-proj + residual)
template<int MODE>
__global__ __launch_bounds__(256) void gemm_bt(
    const unsigned short* __restrict__ A,
    const unsigned short* __restrict__ Bt,
    int M, int N, int K,
    const float* __restrict__ bias,
    const float* __restrict__ extra,
    unsigned short* __restrict__ outb)
{
  int m0 = blockIdx.y * 128, n0 = blockIdx.x * 128;
  if (MODE == 6){                      // split-K: offset into the k-half
    int z = blockIdx.z;
    A    += (size_t)z * (K >> 1);
    Bt   += (size_t)z * (K >> 1);
    outb += (size_t)z * (size_t)M * N;
  }
  const int KL = (MODE == 6) ? (K >> 1) : K;
  const int tid = threadIdx.x, w = tid >> 6, l = tid & 63;
  const int wm = w >> 1, wn = w & 1;
  __shared__ unsigned short lA[2][128 * 64];
  __shared__ unsigned short lB[2][128 * 64];
  f32x4 acc[4][4];
  const f32x4 z4 = {0.f, 0.f, 0.f, 0.f};
  #pragma unroll
  for (int i = 0; i < 4; i++){
    #pragma unroll
    for (int j = 0; j < 4; j++) acc[i][j] = z4;
  }
  const int srow = w * 8 + (l >> 3);
  const int sc = l & 7;

  #pragma unroll
  for (int j = 0; j < 4; j++){
    int row = j * 32 + srow;
    gload16(A + (size_t)(m0 + row) * K + ((sc ^ (row & 7)) << 3),
            &lA[0][0] + j * 2048 + w * 512);
    gload16(Bt + (size_t)(n0 + row) * K + ((sc ^ (row & 7)) << 3),
            &lB[0][0] + j * 2048 + w * 512);
  }
  __syncthreads();

  int cur = 0;
  for (int k0 = 0; k0 < KL; k0 += 64, cur ^= 1){
    if (k0 + 64 < KL){
      #pragma unroll
      for (int j = 0; j < 4; j++){
        int row = j * 32 + srow;
        gload16(A + (size_t)(m0 + row) * K + k0 + 64 + ((sc ^ (row & 7)) << 3),
                &lA[cur ^ 1][0] + j * 2048 + w * 512);
        gload16(Bt + (size_t)(n0 + row) * K + k0 + 64 + ((sc ^ (row & 7)) << 3),
                &lB[cur ^ 1][0] + j * 2048 + w * 512);
      }
    }
    bf16x8 af[4][2], bv[4][2];
    #pragma unroll
    for (int kk = 0; kk < 2; kk++){
      #pragma unroll
      for (int f = 0; f < 4; f++){
        int ra = wm * 64 + f * 16 + (l & 15);
        af[f][kk] = *(const bf16x8*)((const char*)&lA[cur][0] + ra * 128 +
                      (((kk * 4 + (l >> 4)) ^ (ra & 7)) << 4));
        int rb = wn * 64 + f * 16 + (l & 15);
        bv[f][kk] = *(const bf16x8*)((const char*)&lB[cur][0] + rb * 128 +
                      (((kk * 4 + (l >> 4)) ^ (rb & 7)) << 4));
      }
    }
    #pragma unroll
    for (int mf = 0; mf < 4; mf++){
      #pragma unroll
      for (int nf = 0; nf < 4; nf++){
        #pragma unroll
        for (int kk = 0; kk < 2; kk++)
          acc[mf][nf] = mfma16(af[mf][kk], bv[nf][kk], acc[mf][nf]);
      }
    }
    __syncthreads();
  }

  #pragma unroll
  for (int mf = 0; mf < 4; mf++){
    #pragma unroll
    for (int r = 0; r < 4; r++){
      int row = m0 + wm * 64 + mf * 16 + (l >> 4) * 4 + r;
      #pragma unroll
      for (int nf = 0; nf < 4; nf++){
        int col = n0 + wn * 64 + nf * 16 + (l & 15);
        if (MODE == 6){
          outb[(size_t)row * N + col] = f2bf(acc[mf][nf][r]);
        } else if (MODE == 3){
          float v = acc[mf][nf][r] + bias[col];
          outb[(size_t)row * N + col] = f2bf(fmaxf(v, 0.f));
        } else {  // MODE 7
          float v = acc[mf][nf][r] + bias[col] + extra[(size_t)row * N + col];
          outb[(size_t)row * N + col] = f2bf(v);
        }
      }
    }
  }
}

// ---------------------------------------------------------------------------
// flash attention, SWAPPED QK^T, FIXED-m exp2 softmax, QBLK=64 (R12-proven).
// grid (L/64, H, B) = 1024 blocks, block 256 (4 waves x 16 q-rows).
// LDS 40KB -> 4 blocks/CU.
__global__ __launch_bounds__(256, 4) void flash_attn(
    const unsigned short* __restrict__ qkv,
    const unsigned short* __restrict__ vT,
    const unsigned short* __restrict__ cdm,   // cd*LOG2E + 8
    const float* __restrict__ rmax,           // max_k of stored cdm
    unsigned short* __restrict__ y)
{
  const int b = blockIdx.z, h = blockIdx.y, q0 = blockIdx.x * 64;
  const int tid = threadIdx.x, w = tid >> 6, l = tid & 63;
  const int ql = l & 15, lg = l >> 4;
  __shared__ unsigned short QPs[64 * 64];    //  8KB: Q staging; reused as P
  __shared__ unsigned short Ks[2][64 * 64];  // 16KB dbuf
  __shared__ unsigned short Vs[2][64 * 64];  // 16KB dbuf

  const int srow = w * 8 + (l >> 3);
  const int sc = l & 7;
  const unsigned short* kbase = qkv + (size_t)b * Ll * 1536 + 512 + h * DHd;
  const unsigned short* vbase = vT + (size_t)(b * Hh + h) * DHd * Ll;

  // prologue: stage Q + tile 0 of K/V
  #pragma unroll
  for (int j = 0; j < 2; j++){
    int row = j * 32 + srow;
    gload16(qkv + (size_t)(b * Ll + q0 + row) * 1536 + h * DHd + ((sc ^ (row & 7)) << 3),
            QPs + j * 2048 + w * 512);
    gload16(kbase + (size_t)row * 1536 + ((sc ^ (row & 7)) << 3),
            &Ks[0][0] + j * 2048 + w * 512);
    gload16(vbase + (size_t)row * Ll + ((sc ^ (row & 7)) << 3),
            &Vs[0][0] + j * 2048 + w * 512);
  }

  const int qg = q0 + w * 16 + ql;                 // this lane's q-row
  const float rmx8 = rmax[b * Ll + qg] - 8.f;      // diag correction
  const unsigned short* cdrow = cdm + (size_t)(b * Ll + qg) * Ll;

  // register-prefetch cd bias for tile 0
  uint2 cdn[4];
  #pragma unroll
  for (int nf = 0; nf < 4; nf++)
    cdn[nf] = *(const uint2*)(cdrow + nf * 16 + lg * 4);

  f32x4 o[4];
  const f32x4 z4 = {0.f, 0.f, 0.f, 0.f};
  #pragma unroll
  for (int nf = 0; nf < 4; nf++) o[nf] = z4;
  float lsum = 0.f;

  __syncthreads();   // Q + tile 0 resident

  // hoist Q B-fragments (constant over k-loop); QPs region free afterwards
  bf16x8 qa[2];
  #pragma unroll
  for (int kk = 0; kk < 2; kk++){
    int ra = w * 16 + ql;
    qa[kk] = *(const bf16x8*)((const char*)QPs + ra * 128 +
               (((kk * 4 + lg) ^ (ql & 7)) << 4));
  }

  const int NT = Ll / 64;
  for (int t = 0; t < NT; ++t){
    const int k0 = t * 64;
    const int cur = t & 1;

    uint2 cdc[4];                       // this tile's bias (prefetched last tile)
    #pragma unroll
    for (int nf = 0; nf < 4; nf++) cdc[nf] = cdn[nf];

    if (t + 1 < NT){
      const int kn = k0 + 64;
      #pragma unroll
      for (int nf = 0; nf < 4; nf++)    // prefetch next tile's bias
        cdn[nf] = *(const uint2*)(cdrow + kn + nf * 16 + lg * 4);
      #pragma unroll
      for (int j = 0; j < 2; j++){      // stage next K/V (overlaps compute)
        int row = j * 32 + srow;
        gload16(kbase + (size_t)(kn + row) * 1536 + ((sc ^ (row & 7)) << 3),
                &Ks[cur ^ 1][0] + j * 2048 + w * 512);
        gload16(vbase + (size_t)row * Ll + kn + ((sc ^ (row & 7)) << 3),
                &Vs[cur ^ 1][0] + j * 2048 + w * 512);
      }
    }

    // S^T = K Q^T : lane gets q = w*16+ql, k = nf*16 + lg*4 + r
    f32x4 s[4];
    #pragma unroll
    for (int nf = 0; nf < 4; nf++){
      s[nf] = z4;
      #pragma unroll
      for (int kk = 0; kk < 2; kk++){
        int rb = nf * 16 + ql;
        bf16x8 kb = *(const bf16x8*)((const char*)Ks[cur] + rb * 128 +
                      (((kk * 4 + lg) ^ (ql & 7)) << 4));
        s[nf] = mfma16(kb, qa[kk], s[nf]);
      }
    }

    // ---- fixed-m softmax: p = 2^(qk*c - cdm'), no running max ----
    float sv[16];
    #pragma unroll
    for (int nf = 0; nf < 4; nf++){
      float c0 = __uint_as_float(cdc[nf].x << 16);
      float c1 = __uint_as_float(cdc[nf].x & 0xffff0000u);
      float c2 = __uint_as_float(cdc[nf].y << 16);
      float c3 = __uint_as_float(cdc[nf].y & 0xffff0000u);
      sv[nf * 4 + 0] = fmaf(s[nf][0], 0.125f * LOG2E, -c0);
      sv[nf * 4 + 1] = fmaf(s[nf][1], 0.125f * LOG2E, -c1);
      sv[nf * 4 + 2] = fmaf(s[nf][2], 0.125f * LOG2E, -c2);
      sv[nf * 4 + 3] = fmaf(s[nf][3], 0.125f * LOG2E, -c3);
    }
    if (k0 == q0){            // diagonal tile: subtract (rmax_stored - 8)
      #pragma unroll
      for (int nf = 0; nf < 4; nf++) if (nf == w){
        #pragma unroll
        for (int r = 0; r < 4; r++)
          if (lg * 4 + r == ql) sv[nf * 4 + r] -= rmx8;
      }
    }

    float p[16], ps = 0.f;
    #pragma unroll
    for (int i = 0; i < 16; i++){ p[i] = exp2_hw(sv[i]); ps += p[i]; }
    lsum += ps;                         // per-lane partial; reduce at end

    // P -> LDS (wave-private region of QPs), packed b64 per nf
    #pragma unroll
    for (int nf = 0; nf < 4; nf++){
      unsigned d0, d1;
      asm("v_cvt_pk_bf16_f32 %0, %1, %2" : "=v"(d0) : "v"(p[nf*4+0]), "v"(p[nf*4+1]));
      asm("v_cvt_pk_bf16_f32 %0, %1, %2" : "=v"(d1) : "v"(p[nf*4+2]), "v"(p[nf*4+3]));
      uint2 pk2; pk2.x = d0; pk2.y = d1;
      *(uint2*)((char*)QPs + w * 2048 + ql * 128 +
                ((nf * 32 + lg * 8) ^ ((ql & 7) << 4))) = pk2;
    }

    // PV: A = P (rows = q), B = V (cols = dh)
    bf16x8 pa[2];
    #pragma unroll
    for (int kk = 0; kk < 2; kk++)
      pa[kk] = *(const bf16x8*)((const char*)QPs + w * 2048 + ql * 128 +
                 ((((kk * 4 + lg)) ^ (ql & 7)) << 4));
    #pragma unroll
    for (int nf = 0; nf < 4; nf++){
      #pragma unroll
      for (int kk = 0; kk < 2; kk++){
        int rv = nf * 16 + ql;
        bf16x8 vb = *(const bf16x8*)((const char*)Vs[cur] + rv * 128 +
                      (((kk * 4 + lg) ^ (ql & 7)) << 4));
        o[nf] = mfma16(pa[kk], vb, o[nf]);
      }
    }
    __syncthreads();   // staged loads drained; buffers safe to swap
  }

  // epilogue: O rows are q = q0 + w*16 + lg*4 + r; reduce lsum across lg now
  float ltot = lsum;
  ltot += __shfl_xor(ltot, 16, 64);
  ltot += __shfl_xor(ltot, 32, 64);
  float lf[4];
  #pragma unroll
  for (int r = 0; r < 4; r++)
    lf[r] = __shfl(ltot, (l & 48) | (lg * 4 + r), 64);
  #pragma unroll
  for (int nf = 0; nf < 4; nf++){
    #pragma unroll
    for (int r = 0; r < 4; r++){
      int qo = q0 + w * 16 + lg * 4 + r;
      float v = o[nf][r] / lf[r];
      y[(size_t)(b * Ll + qo) * Dd + h * DHd + nf * 16 + ql] = f2bf(v);
    }
  }
}

// ---------------------------------------------------------------------------
// layernorm over D=512, bf16 input -> bf16 out.  grid = B*L, block 256.
__global__ __launch_bounds__(256) void ln_kernel(const unsigned short* __restrict__ in,
                                                 const float* __restrict__ g,
                                                 const float* __restrict__ bt,
                                                 unsigned short* __restrict__ outb){
  int row = blockIdx.x, tid = threadIdx.x;
  unsigned u = ((const unsigned*)(in + (size_t)row * Dd))[tid];
  float vx = __uint_as_float(u << 16);
  float vy = __uint_as_float(u & 0xffff0000u);
  float s = vx + vy, s2 = vx * vx + vy * vy;
  #pragma unroll
  for (int t = 1; t < 64; t <<= 1){ s += __shfl_xor(s, t, 64); s2 += __shfl_xor(s2, t, 64); }
  __shared__ float red[8];
  if ((tid & 63) == 0){ red[tid >> 6] = s; red[4 + (tid >> 6)] = s2; }
  __syncthreads();
  float S  = red[0] + red[1] + red[2] + red[3];
  float S2 = red[4] + red[5] + red[6] + red[7];
  float mu = S * (1.f / 512.f);
  float var = fmaxf(S2 * (1.f / 512.f) - mu * mu, 0.f);
  float rs = rsqrtf(var + 1e-5f);
  int c = tid * 2;
  float o0 = (vx - mu) * rs * g[c] + bt[c];
  float o1 = (vy - mu) * rs * g[c + 1] + bt[c + 1];
  ((unsigned*)(outb + (size_t)row * Dd))[tid] =
      (unsigned)f2bf(o0) | ((unsigned)f2bf(o1) << 16);
}

// ---------------------------------------------------------------------------
// layernorm over (p0 + p1 + bias + extra_bf16): combines FFN2 bf16 split-K
// partials, adds the bf16 residual (LN1 out), then LN.  grid = B*L, block 256.
__global__ __launch_bounds__(256) void ln2p_kernel(
    const unsigned short* __restrict__ p01,     // [2][M][512] bf16 FFN2 partials
    const float* __restrict__ bias,
    const unsigned short* __restrict__ extra,   // residual, bf16 (LN1 out)
    const float* __restrict__ g, const float* __restrict__ bt,
    float* __restrict__ outf)
{
  int row = blockIdx.x, tid = threadIdx.x;
  unsigned u0 = ((const unsigned*)(p01 + (size_t)row * Dd))[tid];
  unsigned u1 = ((const unsigned*)(p01 + (size_t)Bb * Ll * Dd + (size_t)row * Dd))[tid];
  unsigned ex = ((const unsigned*)(extra + (size_t)row * Dd))[tid];
  float a0x = __uint_as_float(u0 << 16),        a0y = __uint_as_float(u0 & 0xffff0000u);
  float a1x = __uint_as_float(u1 << 16),        a1y = __uint_as_float(u1 & 0xffff0000u);
  float ex0 = __uint_as_float(ex << 16),        ex1 = __uint_as_float(ex & 0xffff0000u);
  int c = tid * 2;
  float vx = a0x + a1x + bias[c]     + ex0;
  float vy = a0y + a1y + bias[c + 1] + ex1;
  float s = vx + vy, s2 = vx * vx + vy * vy;
  #pragma unroll
  for (int t = 1; t < 64; t <<= 1){ s += __shfl_xor(s, t, 64); s2 += __shfl_xor(s2, t, 64); }
  __shared__ float red[8];
  if ((tid & 63) == 0){ red[tid >> 6] = s; red[4 + (tid >> 6)] = s2; }
  __syncthreads();
  float S  = red[0] + red[1] + red[2] + red[3];
  float S2 = red[4] + red[5] + red[6] + red[7];
  float mu = S * (1.f / 512.f);
  float var = fmaxf(S2 * (1.f / 512.f) - mu * mu, 0.f);
  float rs = rsqrtf(var + 1e-5f);
  float o0 = (vx - mu) * rs * g[c] + bt[c];
  float o1 = (vy - mu) * rs * g[c + 1] + bt[c + 1];
  float2 ov; ov.x = o0; ov.y = o1;
  ((float2*)(outf + (size_t)row * Dd))[tid] = ov;
}

// ---------------------------------------------------------------------------
extern "C" void kernel_launch(void* const* d_in, const int* in_sizes, int n_in,
                              void* d_out, int out_size, void* d_ws, size_t ws_size,
                              hipStream_t stream){
  const float* x     = (const float*)d_in[0];
  const float* nmask = (const float*)d_in[1];
  const float* wq = (const float*)d_in[2];  const float* bq = (const float*)d_in[3];
  const float* wk = (const float*)d_in[4];  const float* bk = (const float*)d_in[5];
  const float* wv = (const float*)d_in[6];  const float* bv = (const float*)d_in[7];
  const float* wo = (const float*)d_in[8];  const float* bo = (const float*)d_in[9];
  const float* ln1g = (const float*)d_in[10]; const float* ln1b = (const float*)d_in[11];
  const float* w1 = (const float*)d_in[12]; const float* b1 = (const float*)d_in[13];
  const float* w2 = (const float*)d_in[14]; const float* b2 = (const float*)d_in[15];
  const float* ln2g = (const float*)d_in[16]; const float* ln2b = (const float*)d_in[17];
  float* outp = (float*)d_out;
  char* ws = (char*)d_ws;

  // workspace layout (bytes)
  unsigned short* xbf   = (unsigned short*)(ws + 0);          //  8 MB
  float* sq   = (float*)(ws + 8388608);                       //  32 KB
  float* rmax = (float*)(ws + 8421376);                       //  32 KB
  unsigned short* wqkvT = (unsigned short*)(ws + 8454144);    //  1.5 MB (1536 x 512)
  unsigned short* woT   = (unsigned short*)(ws + 10027008);   //  512 KB
  unsigned short* w1T   = (unsigned short*)(ws + 10551296);   //  2 MB
  unsigned short* w2T   = (unsigned short*)(ws + 12648448);   //  2 MB
  unsigned short* cdm   = (unsigned short*)(ws + 14745600);   // 32 MB (later reused as h1)
  unsigned short* qkv   = (unsigned short*)(ws + 48300032);   // 24 MB (b,l,1536; v-slice unused)
  unsigned short* vT    = (unsigned short*)(ws + 73465856);   //  8 MB
  unsigned short* yb    = (unsigned short*)(ws + 81854464);   //  8 MB
  unsigned short* resb  = (unsigned short*)(ws + 90243072);   //  8 MB (attn residual, bf16)
  unsigned short* p01   = (unsigned short*)(ws + 98631680);   // 16 MB FFN2 bf16 partials
  unsigned short* h1  = cdm;    // reuse (cdist dead after attention)
  unsigned short* Xbf = qkv;    // reuse (qkv dead after attention); LN1 out bf16

  prep_all<<<3072 + Bb * Ll, 256, 0, stream>>>(x, wq, wk, wv, wo, w1, w2,
                                               xbf, sq, rmax, wqkvT, woT, w1T, w2T);

  // FUSED: triangular cdist (0..543) + QKV proj (544..1311, v written to vT)
  gemm_cq<<<1312, 256, 0, stream>>>(xbf, wqkvT, bq, bk, bv,
                                    cdm, qkv, vT, sq, rmax, nmask);

  flash_attn<<<dim3(Ll / 64, Hh, Bb), 256, 0, stream>>>(qkv, vT, cdm, rmax, yb);

  // out projection + residual -> resb (bf16)
  gemm_bt<7><<<dim3(4, 64, 1), 256, 0, stream>>>(yb, woT, Bb * Ll, Dd, Dd,
      bo, x, resb);

  // LN1 (bf16 in) -> bf16 out (residual for LN2)
  ln_kernel<<<Bb * Ll, 256, 0, stream>>>(resb, ln1g, ln1b, Xbf);

  // FFN
  gemm_bt<3><<<dim3(16, 64, 1), 256, 0, stream>>>(Xbf, w1T, Bb * Ll, 4 * Dd, Dd,
      b1, nullptr, h1);
  // FFN2 split-K x2 -> bf16 partials in p01 (p0 at 0, p1 at +M*N)
  gemm_bt<6><<<dim3(4, 64, 2), 256, 0, stream>>>(h1, w2T, Bb * Ll, Dd, 4 * Dd,
      nullptr, nullptr, p01);

  ln2p_kernel<<<Bb * Ll, 256, 0, stream>>>(p01, b2, Xbf, ln2g, ln2b, outp);
}